// Round 2
// baseline (4487.252 us; speedup 1.0000x reference)
//
#include <hip/hip_runtime.h>
#include <hip/hip_bf16.h>
#include <cstddef>

#define DEV __device__ __forceinline__

constexpr int Bb  = 4;
constexpr int Nn  = 2048;
constexpr int MK  = 256;
constexpr int Dd  = 512;
constexpr int Hh  = 8;
constexpr int DH  = 64;
constexpr int QLD = 1536;   // qkv row stride (3*512)
constexpr int MLPD = 2048;
constexpr float SCALE = 0.125f;   // 64^-0.5
constexpr float NEGV  = -1e9f;

DEV float4 ldf4(const float* p) { return *reinterpret_cast<const float4*>(p); }

DEV float waveMax(float v) {
#pragma unroll
  for (int o = 32; o; o >>= 1) v = fmaxf(v, __shfl_xor(v, o));
  return v;
}
DEV float waveSum(float v) {
#pragma unroll
  for (int o = 32; o; o >>= 1) v += __shfl_xor(v, o);
  return v;
}

// block = 256 threads (4 waves). red must be float[8] shared.
DEV float blockMax256(float v, float* red) {
  v = waveMax(v);
  __syncthreads();                    // protect red from previous use
  if ((threadIdx.x & 63) == 0) red[threadIdx.x >> 6] = v;
  __syncthreads();
  return fmaxf(fmaxf(red[0], red[1]), fmaxf(red[2], red[3]));
}
DEV float blockSum256(float v, float* red) {
  v = waveSum(v);
  __syncthreads();
  if ((threadIdx.x & 63) == 0) red[threadIdx.x >> 6] = v;
  __syncthreads();
  return red[0] + red[1] + red[2] + red[3];
}
DEV float2 blockSum2_256(float a, float b, float* red) {
  a = waveSum(a); b = waveSum(b);
  __syncthreads();
  if ((threadIdx.x & 63) == 0) { red[threadIdx.x >> 6] = a; red[4 + (threadIdx.x >> 6)] = b; }
  __syncthreads();
  return make_float2(red[0] + red[1] + red[2] + red[3],
                     red[4] + red[5] + red[6] + red[7]);
}

DEV float gelu_f(float x) { return 0.5f * x * (1.f + erff(x * 0.70710678118654752f)); }

// ---------------- LayerNorm: one wave per 512-float row ----------------
__global__ __launch_bounds__(64)
void ln_kernel(const float* __restrict__ in, const float* __restrict__ gw,
               const float* __restrict__ bw, float* __restrict__ out) {
  const int row = blockIdx.x;
  const int t = threadIdx.x;
  const float* p = in + (size_t)row * Dd + t * 8;
  float4 v0 = ldf4(p), v1 = ldf4(p + 4);
  float s = v0.x + v0.y + v0.z + v0.w + v1.x + v1.y + v1.z + v1.w;
  float q = v0.x*v0.x + v0.y*v0.y + v0.z*v0.z + v0.w*v0.w
          + v1.x*v1.x + v1.y*v1.y + v1.z*v1.z + v1.w*v1.w;
  s = waveSum(s); q = waveSum(q);
  const float mu = s * (1.f / Dd);
  const float rstd = rsqrtf(fmaxf(q * (1.f / Dd) - mu * mu, 0.f) + 1e-5f);
  float4 g0 = ldf4(gw + t * 8), g1 = ldf4(gw + t * 8 + 4);
  float4 b0 = ldf4(bw + t * 8), b1 = ldf4(bw + t * 8 + 4);
  float4 o0, o1;
  o0.x = (v0.x - mu) * rstd * g0.x + b0.x;
  o0.y = (v0.y - mu) * rstd * g0.y + b0.y;
  o0.z = (v0.z - mu) * rstd * g0.z + b0.z;
  o0.w = (v0.w - mu) * rstd * g0.w + b0.w;
  o1.x = (v1.x - mu) * rstd * g1.x + b1.x;
  o1.y = (v1.y - mu) * rstd * g1.y + b1.y;
  o1.z = (v1.z - mu) * rstd * g1.z + b1.z;
  o1.w = (v1.w - mu) * rstd * g1.w + b1.w;
  float* op = out + (size_t)row * Dd + t * 8;
  *reinterpret_cast<float4*>(op) = o0;
  *reinterpret_cast<float4*>(op + 4) = o1;
}

// ---------------- f32 tiled GEMM: C = A(MxK) @ B(KxN) [+bias][gelu][+res] ----------------
template<bool BIAS_, bool GELU_, bool RES_>
__global__ __launch_bounds__(256)
void gemm_kernel(const float* __restrict__ A, const float* __restrict__ Bm,
                 const float* __restrict__ bias, const float* __restrict__ Rres,
                 float* __restrict__ C, int Mrows, int K, int Ncols) {
  __shared__ __align__(16) float As[16][64];
  __shared__ __align__(16) float Bs[16][64];
  const int tid = threadIdx.x;
  const int tx = tid & 15, ty = tid >> 4;
  const int bm = blockIdx.y * 64, bn = blockIdx.x * 64;
  float acc[4][4] = {};
  const int ra = tid >> 2, ca = (tid & 3) * 4;   // A-tile: row 0..63, col-quad
  const int rb = tid >> 4, cb = (tid & 15) * 4;  // B-tile: row 0..15, col-quad
  const bool aval = (bm + ra) < Mrows;
  const float* Ap = A + (size_t)(bm + ra) * K + ca;
  const float* Bp = Bm + (size_t)rb * Ncols + bn + cb;
  for (int k0 = 0; k0 < K; k0 += 16) {
    float4 av = aval ? ldf4(Ap + k0) : make_float4(0.f, 0.f, 0.f, 0.f);
    float4 bv = ldf4(Bp + (size_t)k0 * Ncols);
    As[ca + 0][ra] = av.x; As[ca + 1][ra] = av.y;
    As[ca + 2][ra] = av.z; As[ca + 3][ra] = av.w;
    *reinterpret_cast<float4*>(&Bs[rb][cb]) = bv;
    __syncthreads();
#pragma unroll
    for (int kk = 0; kk < 16; ++kk) {
      float4 a4 = *reinterpret_cast<float4*>(&As[kk][ty * 4]);
      float4 b4 = *reinterpret_cast<float4*>(&Bs[kk][tx * 4]);
      acc[0][0] = fmaf(a4.x, b4.x, acc[0][0]); acc[0][1] = fmaf(a4.x, b4.y, acc[0][1]);
      acc[0][2] = fmaf(a4.x, b4.z, acc[0][2]); acc[0][3] = fmaf(a4.x, b4.w, acc[0][3]);
      acc[1][0] = fmaf(a4.y, b4.x, acc[1][0]); acc[1][1] = fmaf(a4.y, b4.y, acc[1][1]);
      acc[1][2] = fmaf(a4.y, b4.z, acc[1][2]); acc[1][3] = fmaf(a4.y, b4.w, acc[1][3]);
      acc[2][0] = fmaf(a4.z, b4.x, acc[2][0]); acc[2][1] = fmaf(a4.z, b4.y, acc[2][1]);
      acc[2][2] = fmaf(a4.z, b4.z, acc[2][2]); acc[2][3] = fmaf(a4.z, b4.w, acc[2][3]);
      acc[3][0] = fmaf(a4.w, b4.x, acc[3][0]); acc[3][1] = fmaf(a4.w, b4.y, acc[3][1]);
      acc[3][2] = fmaf(a4.w, b4.z, acc[3][2]); acc[3][3] = fmaf(a4.w, b4.w, acc[3][3]);
    }
    __syncthreads();
  }
  const int col = bn + tx * 4;
#pragma unroll
  for (int i = 0; i < 4; ++i) {
    int row = bm + ty * 4 + i;
    if (row >= Mrows) break;
    float4 v = make_float4(acc[i][0], acc[i][1], acc[i][2], acc[i][3]);
    if (BIAS_) {
      float4 bb = ldf4(bias + col);
      v.x += bb.x; v.y += bb.y; v.z += bb.z; v.w += bb.w;
    }
    if (GELU_) { v.x = gelu_f(v.x); v.y = gelu_f(v.y); v.z = gelu_f(v.z); v.w = gelu_f(v.w); }
    if (RES_) {
      float4 r = ldf4(Rres + (size_t)row * Ncols + col);
      v.x += r.x; v.y += r.y; v.z += r.z; v.w += r.w;
    }
    *reinterpret_cast<float4*>(C + (size_t)row * Ncols + col) = v;
  }
}

// ------------- attention over x-tokens: dots -> 2 softmaxes -> PV, fused -------------
// grid (B*H, N/128), block 256. Thread j holds K-row j in registers, V in LDS.
__global__ __launch_bounds__(256)
void attn_x_kernel(const float* __restrict__ tqkv, const float* __restrict__ kqkv,
                   const float* __restrict__ rd, const float* __restrict__ mask,
                   const float* __restrict__ kmask,
                   float* __restrict__ x_pre, float* __restrict__ attn_out) {
  constexpr int ITILE = 128;
  __shared__ __align__(16) float kv_s[MK][DH];
  __shared__ __align__(16) float q_s[DH];
  __shared__ float pbuf[MK];
  __shared__ float red8[8];
  __shared__ float redpv[4][DH];
  __shared__ float mask_s;
  const int tid = threadIdx.x;
  const int bh = blockIdx.x, b = bh >> 3, h = bh & 7;
  float kk[DH];
  {
    const float* kp = kqkv + ((size_t)(b * MK + tid)) * QLD + Dd + h * DH;
#pragma unroll
    for (int q4 = 0; q4 < 16; ++q4) {
      float4 v = ldf4(kp + q4 * 4);
      kk[q4 * 4 + 0] = v.x; kk[q4 * 4 + 1] = v.y; kk[q4 * 4 + 2] = v.z; kk[q4 * 4 + 3] = v.w;
    }
    const float* vp = kqkv + ((size_t)(b * MK + tid)) * QLD + 2 * Dd + h * DH;
#pragma unroll
    for (int q4 = 0; q4 < 16; ++q4)
      *reinterpret_cast<float4*>(&kv_s[tid][q4 * 4]) = ldf4(vp + q4 * 4);
  }
  const float kmj = kmask[b * MK + tid];
  const float* rdp = rd + ((size_t)(b * MK + tid)) * Nn;          // row j of rd
  float* aop = attn_out + ((size_t)(bh * MK + tid)) * Nn;         // row j of atten[l][b][h]
  const int i0 = blockIdx.y * ITILE;
  __syncthreads();
  for (int il = 0; il < ITILE; ++il) {
    const int i = i0 + il;
    if (tid < DH) q_s[tid] = tqkv[((size_t)(b * Nn + i)) * QLD + h * DH + tid];
    if (tid == 0) mask_s = mask[b * Nn + i];
    __syncthreads();
    float dot = 0.f;
#pragma unroll
    for (int q4 = 0; q4 < 16; ++q4) {
      float4 qv = ldf4(&q_s[q4 * 4]);
      dot = fmaf(qv.x, kk[q4 * 4 + 0], dot);
      dot = fmaf(qv.y, kk[q4 * 4 + 1], dot);
      dot = fmaf(qv.z, kk[q4 * 4 + 2], dot);
      dot = fmaf(qv.w, kk[q4 * 4 + 3], dot);
    }
    const float dm = (mask_s * kmj < 0.5f) ? NEGV : dot * SCALE;
    const float mx = blockMax256(dm, red8);
    const float e1 = __expf(dm - mx);
    const float e24 = __expf(24.f * (dm - mx));
    const float2 ss = blockSum2_256(e1, e24, red8);
    const float rdv = rdp[i];
    aop[i] = e24 / ss.y * rdv;          // atten[l][b,h,j,i] = attn_t[b,h,i,j]
    pbuf[tid] = e1 / ss.x * rdv;
    __syncthreads();
    const int d = tid & 63, g = tid >> 6;
    float acc = 0.f;
#pragma unroll 8
    for (int jj = 0; jj < 64; ++jj)
      acc = fmaf(pbuf[g * 64 + jj], kv_s[g * 64 + jj][d], acc);
    redpv[g][d] = acc;
    __syncthreads();
    if (tid < DH)
      x_pre[((size_t)(b * Nn + i)) * Dd + h * DH + tid] =
          redpv[0][tid] + redpv[1][tid] + redpv[2][tid] + redpv[3][tid];
    __syncthreads();
  }
}

// ------------- attention over k-tokens: one block per (j, b*h) -------------
// grid (MK, B*H), block 256. p-row (2048) in LDS; softmax over x-tokens; PV vs tv.
__global__ __launch_bounds__(256)
void attn_k_kernel(const float* __restrict__ tqkv, const float* __restrict__ kqkv,
                   const float* __restrict__ rd, const float* __restrict__ mask,
                   const float* __restrict__ kmask, float* __restrict__ kx_pre) {
  __shared__ float p[Nn];                      // 8 KB
  __shared__ __align__(16) float q_s[DH];
  __shared__ float red8[8];
  __shared__ float redpv[4][DH];
  const int tid = threadIdx.x;
  const int j  = blockIdx.x;
  const int bh = blockIdx.y, b = bh >> 3, h = bh & 7;
  if (tid < DH) q_s[tid] = kqkv[((size_t)(b * MK + j)) * QLD + h * DH + tid];
  const float kmj = kmask[b * MK + j];
  __syncthreads();
  float lm = -3.4e38f;
  for (int c = 0; c < Nn / 256; ++c) {
    const int i = c * 256 + tid;
    const float* tkp = tqkv + ((size_t)(b * Nn + i)) * QLD + Dd + h * DH;
    float a = 0.f;
#pragma unroll
    for (int q4 = 0; q4 < 16; ++q4) {
      float4 kv4 = ldf4(tkp + q4 * 4);
      float4 qv = ldf4(&q_s[q4 * 4]);
      a = fmaf(qv.x, kv4.x, a);
      a = fmaf(qv.y, kv4.y, a);
      a = fmaf(qv.z, kv4.z, a);
      a = fmaf(qv.w, kv4.w, a);
    }
    const float dm = (mask[b * Nn + i] * kmj < 0.5f) ? NEGV : a * SCALE;
    p[i] = dm;
    lm = fmaxf(lm, dm);
  }
  const float mx = blockMax256(lm, red8);
  float ls = 0.f;
  for (int c = 0; c < Nn / 256; ++c) {
    const int i = c * 256 + tid;
    float e = __expf(p[i] - mx);
    p[i] = e;
    ls += e;
  }
  const float s = blockSum256(ls, red8);
  const float inv = 1.f / s;
  const float* rp = rd + ((size_t)(b * MK + j)) * Nn;
  for (int c = 0; c < Nn / 256; ++c) {
    const int i = c * 256 + tid;
    p[i] *= inv * rp[i];
  }
  __syncthreads();
  const int d = tid & 63, g = tid >> 6;
  const float* tvp = tqkv + ((size_t)(b * Nn)) * QLD + 2 * Dd + h * DH + d;
  float acc = 0.f;
  for (int i4 = 0; i4 < 512; ++i4) {
    const int i = g * 512 + i4;
    acc = fmaf(p[i], tvp[(size_t)i * QLD], acc);
  }
  redpv[g][d] = acc;
  __syncthreads();
  if (tid < DH)
    kx_pre[((size_t)(b * MK + j)) * Dd + h * DH + tid] =
        redpv[0][tid] + redpv[1][tid] + redpv[2][tid] + redpv[3][tid];
}

// ------------- cls-token attention: grid B*H, block 256 -------------
__global__ __launch_bounds__(256)
void attn_c_kernel(const float* __restrict__ cqkv, const float* __restrict__ kqkv,
                   const float* __restrict__ mask, const float* __restrict__ kmask,
                   float* __restrict__ c_pre) {
  __shared__ __align__(16) float kv_s[MK][DH];
  __shared__ __align__(16) float q_s[DH];
  __shared__ float pbuf[MK];
  __shared__ float red8[8];
  __shared__ float redpv[4][DH];
  const int tid = threadIdx.x;
  const int bh = blockIdx.x, b = bh >> 3, h = bh & 7;
  const float* vp = kqkv + ((size_t)(b * MK + tid)) * QLD + 2 * Dd + h * DH;
#pragma unroll
  for (int q4 = 0; q4 < 16; ++q4)
    *reinterpret_cast<float4*>(&kv_s[tid][q4 * 4]) = ldf4(vp + q4 * 4);
  if (tid < DH) q_s[tid] = cqkv[(size_t)b * QLD + h * DH + tid];
  __syncthreads();
  const float* kp = kqkv + ((size_t)(b * MK + tid)) * QLD + Dd + h * DH;
  float dot = 0.f;
#pragma unroll
  for (int q4 = 0; q4 < 16; ++q4) {
    float4 kv4 = ldf4(kp + q4 * 4);
    float4 qv = ldf4(&q_s[q4 * 4]);
    dot = fmaf(qv.x, kv4.x, dot);
    dot = fmaf(qv.y, kv4.y, dot);
    dot = fmaf(qv.z, kv4.z, dot);
    dot = fmaf(qv.w, kv4.w, dot);
  }
  const float dm = (mask[(size_t)b * Nn] * kmask[b * MK + tid] < 0.5f) ? NEGV : dot * SCALE;
  const float mx = blockMax256(dm, red8);
  const float e = __expf(dm - mx);
  const float s = blockSum256(e, red8);
  pbuf[tid] = e / s;
  __syncthreads();
  const int d = tid & 63, g = tid >> 6;
  float acc = 0.f;
#pragma unroll 8
  for (int jj = 0; jj < 64; ++jj)
    acc = fmaf(pbuf[g * 64 + jj], kv_s[g * 64 + jj][d], acc);
  redpv[g][d] = acc;
  __syncthreads();
  if (tid < DH)
    c_pre[(size_t)b * Dd + h * DH + tid] =
        redpv[0][tid] + redpv[1][tid] + redpv[2][tid] + redpv[3][tid];
}

// ------------- output writers (float32 outputs!) -------------
__global__ void kreps_kernel(const float* __restrict__ kx, const float* __restrict__ kmask,
                             float* __restrict__ o) {
  const int idx = blockIdx.x * 256 + threadIdx.x;   // B*MK*Dd
  const int bj = idx >> 9;
  const float keep = (kmask[bj] >= 0.5f) ? 1.f : 0.f;
  o[idx] = kx[idx] * keep;
}
__global__ void cout_kernel(const float* __restrict__ c_s, float* __restrict__ o) {
  const int idx = blockIdx.x * 256 + threadIdx.x;
  o[idx] = c_s[idx];
}

// ------------- host-side GEMM wrapper -------------
template<bool BIAS_, bool GELU_, bool RES_>
static void gemm(const float* A, const float* Bm, const float* bias, const float* R,
                 float* C, int M, int K, int N, hipStream_t s) {
  dim3 grid(N / 64, (M + 63) / 64);
  gemm_kernel<BIAS_, GELU_, RES_><<<grid, 256, 0, s>>>(A, Bm, bias, R, C, M, K, N);
}

extern "C" void kernel_launch(void* const* d_in, const int* in_sizes, int n_in,
                              void* d_out, int out_size, void* d_ws, size_t ws_size,
                              hipStream_t stream) {
  (void)in_sizes; (void)n_in; (void)out_size; (void)ws_size;
  const float* x_in  = (const float*)d_in[0];
  const float* kx_in = (const float*)d_in[1];
  const float* rd    = (const float*)d_in[2];
  const float* c_in  = (const float*)d_in[3];
  const float* mask  = (const float*)d_in[4];
  const float* kmask = (const float*)d_in[5];
  const float* ln1g  = (const float*)d_in[6];
  const float* ln1b  = (const float*)d_in[7];
  const float* Wqkv  = (const float*)d_in[8];
  const float* Woutw = (const float*)d_in[9];
  const float* boutw = (const float*)d_in[10];
  const float* ln2g  = (const float*)d_in[11];
  const float* ln2b  = (const float*)d_in[12];
  const float* W1    = (const float*)d_in[13];
  const float* b1    = (const float*)d_in[14];
  const float* W2    = (const float*)d_in[15];
  const float* b2    = (const float*)d_in[16];
  float* out = (float*)d_out;        // reference outputs are float32

  float* ws = (float*)d_ws;
  size_t off = 0;
  auto alloc = [&](size_t n) { float* p = ws + off; off += n; return p; };
  float* x_s    = alloc((size_t)Bb * Nn * Dd);
  float* xn     = alloc((size_t)Bb * Nn * Dd);
  float* kx_s   = alloc((size_t)Bb * MK * Dd);
  float* kxn    = alloc((size_t)Bb * MK * Dd);
  float* c_s    = alloc((size_t)Bb * Dd);
  float* cn     = alloc((size_t)Bb * Dd);
  float* big    = alloc((size_t)Bb * Nn * MLPD);   // tqkv (12.58M) / ff hidden (16.78M)
  float* kqkv   = alloc((size_t)Bb * MK * QLD);
  float* cqkv   = alloc((size_t)Bb * QLD);
  float* kx_pre = alloc((size_t)Bb * MK * Dd);
  float* c_pre  = alloc((size_t)Bb * Dd);
  // x_pre lives in big's tail: tqkv uses Bb*Nn*QLD = 12.58M of big's 16.78M.
  float* x_pre  = big + (size_t)Bb * Nn * QLD;

  const size_t CL_OFF = (size_t)2 * Bb * MK * Dd;
  const size_t AT_OFF = CL_OFF + (size_t)Bb * Dd;

  for (int l = 0; l < 2; ++l) {
    const float* xp  = (l == 0) ? x_in  : x_s;
    const float* kxp = (l == 0) ? kx_in : kx_s;
    const float* cp  = (l == 0) ? c_in  : c_s;
    ln_kernel<<<Bb * Nn, 64, 0, stream>>>(xp,  ln1g + l * Dd, ln1b + l * Dd, xn);
    ln_kernel<<<Bb * MK, 64, 0, stream>>>(kxp, ln1g + l * Dd, ln1b + l * Dd, kxn);
    ln_kernel<<<Bb,      64, 0, stream>>>(cp,  ln1g + l * Dd, ln1b + l * Dd, cn);

    const float* Wq = Wqkv + (size_t)l * Dd * QLD;
    gemm<false, false, false>(xn,  Wq, nullptr, nullptr, big,  Bb * Nn, Dd, QLD, stream);
    gemm<false, false, false>(kxn, Wq, nullptr, nullptr, kqkv, Bb * MK, Dd, QLD, stream);
    gemm<false, false, false>(cn,  Wq, nullptr, nullptr, cqkv, Bb,      Dd, QLD, stream);

    attn_x_kernel<<<dim3(Bb * Hh, Nn / 128), 256, 0, stream>>>(
        big, kqkv, rd, mask, kmask, x_pre,
        out + AT_OFF + (size_t)l * Bb * Hh * MK * Nn);
    attn_k_kernel<<<dim3(MK, Bb * Hh), 256, 0, stream>>>(big, kqkv, rd, mask, kmask,
                                                         kx_pre);
    attn_c_kernel<<<Bb * Hh, 256, 0, stream>>>(cqkv, kqkv, mask, kmask, c_pre);

    const float* Wo = Woutw + (size_t)l * Dd * Dd;
    const float* bo = boutw + (size_t)l * Dd;
    gemm<true, false, true>(x_pre,  Wo, bo, xn,  x_s,  Bb * Nn, Dd, Dd, stream);
    gemm<true, false, true>(kx_pre, Wo, bo, kxn, kx_s, Bb * MK, Dd, Dd, stream);
    gemm<true, false, true>(c_pre,  Wo, bo, cn,  c_s,  Bb,      Dd, Dd, stream);

    const float* W1l = W1 + (size_t)l * Dd * MLPD;
    const float* b1l = b1 + (size_t)l * MLPD;
    const float* W2l = W2 + (size_t)l * MLPD * Dd;
    const float* b2l = b2 + (size_t)l * Dd;

    ln_kernel<<<Bb * Nn, 64, 0, stream>>>(x_s, ln2g + l * Dd, ln2b + l * Dd, xn);
    gemm<true, true,  false>(xn,  W1l, b1l, nullptr, big, Bb * Nn, Dd,   MLPD, stream);
    gemm<true, false, true >(big, W2l, b2l, x_s,     x_s, Bb * Nn, MLPD, Dd,   stream);

    ln_kernel<<<Bb * MK, 64, 0, stream>>>(kx_s, ln2g + l * Dd, ln2b + l * Dd, kxn);
    gemm<true, true,  false>(kxn, W1l, b1l, nullptr, big,  Bb * MK, Dd,   MLPD, stream);
    gemm<true, false, true >(big, W2l, b2l, kx_s,    kx_s, Bb * MK, MLPD, Dd,   stream);

    ln_kernel<<<Bb, 64, 0, stream>>>(c_s, ln2g + l * Dd, ln2b + l * Dd, cn);
    gemm<true, true,  false>(cn,  W1l, b1l, nullptr, big, Bb, Dd,   MLPD, stream);
    gemm<true, false, true >(big, W2l, b2l, c_s,     c_s, Bb, MLPD, Dd,   stream);

    kreps_kernel<<<(Bb * MK * Dd) / 256, 256, 0, stream>>>(kx_s, kmask,
                                                           out + (size_t)l * Bb * MK * Dd);
  }
  cout_kernel<<<(Bb * Dd) / 256, 256, 0, stream>>>(c_s, out + CL_OFF);
}

// Round 3
// 1745.934 us; speedup vs baseline: 2.5701x; 2.5701x over previous
//
#include <hip/hip_runtime.h>
#include <hip/hip_bf16.h>
#include <cstddef>

#define DEV __device__ __forceinline__

constexpr int Bb  = 4;
constexpr int Nn  = 2048;
constexpr int MK  = 256;
constexpr int Dd  = 512;
constexpr int Hh  = 8;
constexpr int DH  = 64;
constexpr int QLD = 1536;   // qkv row stride (3*512)
constexpr int MLPD = 2048;
constexpr float SCALE = 0.125f;   // 64^-0.5
constexpr float NEGV  = -1e9f;

typedef __attribute__((ext_vector_type(8))) short short8;
typedef __attribute__((ext_vector_type(4))) float f32x4;

DEV float4 ldf4(const float* p) { return *reinterpret_cast<const float4*>(p); }

DEV float waveMax(float v) {
#pragma unroll
  for (int o = 32; o; o >>= 1) v = fmaxf(v, __shfl_xor(v, o));
  return v;
}
DEV float waveSum(float v) {
#pragma unroll
  for (int o = 32; o; o >>= 1) v += __shfl_xor(v, o);
  return v;
}
DEV float blockMax256(float v, float* red) {
  v = waveMax(v);
  __syncthreads();
  if ((threadIdx.x & 63) == 0) red[threadIdx.x >> 6] = v;
  __syncthreads();
  return fmaxf(fmaxf(red[0], red[1]), fmaxf(red[2], red[3]));
}
DEV float blockSum256(float v, float* red) {
  v = waveSum(v);
  __syncthreads();
  if ((threadIdx.x & 63) == 0) red[threadIdx.x >> 6] = v;
  __syncthreads();
  return red[0] + red[1] + red[2] + red[3];
}
DEV float gelu_f(float x) { return 0.5f * x * (1.f + erff(x * 0.70710678118654752f)); }

// ---------------- LayerNorm: one wave per 512-float row, dual f32+bf16 out ----------------
__global__ __launch_bounds__(64)
void ln_kernel(const float* __restrict__ in, const float* __restrict__ gw,
               const float* __restrict__ bw, float* __restrict__ out,
               __hip_bfloat16* __restrict__ outb) {
  const int row = blockIdx.x;
  const int t = threadIdx.x;
  const float* p = in + (size_t)row * Dd + t * 8;
  float4 v0 = ldf4(p), v1 = ldf4(p + 4);
  float s = v0.x + v0.y + v0.z + v0.w + v1.x + v1.y + v1.z + v1.w;
  float q = v0.x*v0.x + v0.y*v0.y + v0.z*v0.z + v0.w*v0.w
          + v1.x*v1.x + v1.y*v1.y + v1.z*v1.z + v1.w*v1.w;
  s = waveSum(s); q = waveSum(q);
  const float mu = s * (1.f / Dd);
  const float rstd = rsqrtf(fmaxf(q * (1.f / Dd) - mu * mu, 0.f) + 1e-5f);
  float4 g0 = ldf4(gw + t * 8), g1 = ldf4(gw + t * 8 + 4);
  float4 b0 = ldf4(bw + t * 8), b1 = ldf4(bw + t * 8 + 4);
  float o[8];
  o[0] = (v0.x - mu) * rstd * g0.x + b0.x;
  o[1] = (v0.y - mu) * rstd * g0.y + b0.y;
  o[2] = (v0.z - mu) * rstd * g0.z + b0.z;
  o[3] = (v0.w - mu) * rstd * g0.w + b0.w;
  o[4] = (v1.x - mu) * rstd * g1.x + b1.x;
  o[5] = (v1.y - mu) * rstd * g1.y + b1.y;
  o[6] = (v1.z - mu) * rstd * g1.z + b1.z;
  o[7] = (v1.w - mu) * rstd * g1.w + b1.w;
  float* op = out + (size_t)row * Dd + t * 8;
  *reinterpret_cast<float4*>(op)     = make_float4(o[0], o[1], o[2], o[3]);
  *reinterpret_cast<float4*>(op + 4) = make_float4(o[4], o[5], o[6], o[7]);
  if (outb) {
    __hip_bfloat16* ob = outb + (size_t)row * Dd + t * 8;
#pragma unroll
    for (int e = 0; e < 8; ++e) ob[e] = __float2bfloat16(o[e]);
  }
}

// ---------------- legacy f32 tiled GEMM (cls-token path, M=4) ----------------
template<bool BIAS_, bool GELU_, bool RES_>
__global__ __launch_bounds__(256)
void gemm_kernel(const float* __restrict__ A, const float* __restrict__ Bm,
                 const float* __restrict__ bias, const float* __restrict__ Rres,
                 float* __restrict__ C, int Mrows, int K, int Ncols) {
  __shared__ __align__(16) float As[16][64];
  __shared__ __align__(16) float Bs[16][64];
  const int tid = threadIdx.x;
  const int tx = tid & 15, ty = tid >> 4;
  const int bm = blockIdx.y * 64, bn = blockIdx.x * 64;
  float acc[4][4] = {};
  const int ra = tid >> 2, ca = (tid & 3) * 4;
  const int rb = tid >> 4, cb = (tid & 15) * 4;
  const bool aval = (bm + ra) < Mrows;
  const float* Ap = A + (size_t)(bm + ra) * K + ca;
  const float* Bp = Bm + (size_t)rb * Ncols + bn + cb;
  for (int k0 = 0; k0 < K; k0 += 16) {
    float4 av = aval ? ldf4(Ap + k0) : make_float4(0.f, 0.f, 0.f, 0.f);
    float4 bv = ldf4(Bp + (size_t)k0 * Ncols);
    As[ca + 0][ra] = av.x; As[ca + 1][ra] = av.y;
    As[ca + 2][ra] = av.z; As[ca + 3][ra] = av.w;
    *reinterpret_cast<float4*>(&Bs[rb][cb]) = bv;
    __syncthreads();
#pragma unroll
    for (int kk = 0; kk < 16; ++kk) {
      float4 a4 = *reinterpret_cast<float4*>(&As[kk][ty * 4]);
      float4 b4 = *reinterpret_cast<float4*>(&Bs[kk][tx * 4]);
      acc[0][0] = fmaf(a4.x, b4.x, acc[0][0]); acc[0][1] = fmaf(a4.x, b4.y, acc[0][1]);
      acc[0][2] = fmaf(a4.x, b4.z, acc[0][2]); acc[0][3] = fmaf(a4.x, b4.w, acc[0][3]);
      acc[1][0] = fmaf(a4.y, b4.x, acc[1][0]); acc[1][1] = fmaf(a4.y, b4.y, acc[1][1]);
      acc[1][2] = fmaf(a4.y, b4.z, acc[1][2]); acc[1][3] = fmaf(a4.y, b4.w, acc[1][3]);
      acc[2][0] = fmaf(a4.z, b4.x, acc[2][0]); acc[2][1] = fmaf(a4.z, b4.y, acc[2][1]);
      acc[2][2] = fmaf(a4.z, b4.z, acc[2][2]); acc[2][3] = fmaf(a4.z, b4.w, acc[2][3]);
      acc[3][0] = fmaf(a4.w, b4.x, acc[3][0]); acc[3][1] = fmaf(a4.w, b4.y, acc[3][1]);
      acc[3][2] = fmaf(a4.w, b4.z, acc[3][2]); acc[3][3] = fmaf(a4.w, b4.w, acc[3][3]);
    }
    __syncthreads();
  }
  const int col = bn + tx * 4;
#pragma unroll
  for (int i = 0; i < 4; ++i) {
    int row = bm + ty * 4 + i;
    if (row >= Mrows) break;
    float4 v = make_float4(acc[i][0], acc[i][1], acc[i][2], acc[i][3]);
    if (BIAS_) {
      float4 bb = ldf4(bias + col);
      v.x += bb.x; v.y += bb.y; v.z += bb.z; v.w += bb.w;
    }
    if (GELU_) { v.x = gelu_f(v.x); v.y = gelu_f(v.y); v.z = gelu_f(v.z); v.w = gelu_f(v.w); }
    if (RES_) {
      float4 r = ldf4(Rres + (size_t)row * Ncols + col);
      v.x += r.x; v.y += r.y; v.z += r.z; v.w += r.w;
    }
    *reinterpret_cast<float4*>(C + (size_t)row * Ncols + col) = v;
  }
}

// ---------------- bf16 MFMA GEMM ----------------
// C[M,N] = A[M,K] @ Bt[N,K]^T, batched over blockIdx.z. 256 threads.
// EPI: 0 = f32 write; 1 = mask+scale f32 (scores); 2 = +bias +res f32;
//      3 = +bias, gelu, bf16 write; 4 = bf16 write.
struct GArgs {
  const short* A;  long asb; int lda;
  const short* Bt; long bsb; int ldb;
  float* C; __hip_bfloat16* Cb;
  long czo, czi; int ldc;
  const float* bias;
  const float* res; int ldr;
  const float* rowm; int rms;
  const float* colm; int cms;
  int z0, M, N, K;
};

template<int BM, int BN, int EPI>
__global__ __launch_bounds__(256)
void mgemm(GArgs g) {
  constexpr int WMW = (BN >= 128) ? 2 : 4;
  constexpr int WNW = 4 / WMW;
  constexpr int WM = BM / WMW, WN = BN / WNW;
  constexpr int FM = WM / 16, FN = WN / 16;
  __shared__ short As[BM * 64];
  __shared__ short Bs[BN * 64];
  const int tid = threadIdx.x, l = tid & 63, w = tid >> 6;
  const int wm = (WNW == 2) ? (w >> 1) : w;
  const int wn = (WNW == 2) ? (w & 1) : 0;
  const int bx = blockIdx.x, by = blockIdx.y, z = blockIdx.z;
  const short* Ab = g.A + (size_t)z * g.asb;
  const short* Bb = g.Bt + (size_t)z * g.bsb;
  f32x4 acc[FM][FN] = {};
  const int lr = l & 15, lg = l >> 4;

  for (int k0 = 0; k0 < g.K; k0 += 64) {
    __syncthreads();
#pragma unroll
    for (int it = 0; it < BM / 32; ++it) {
      int idx = tid + it * 256, r = idx >> 3, c8 = (idx & 7) * 8;
      int gm = by * BM + r;
      short8 v = {};
      if (gm < g.M) v = *reinterpret_cast<const short8*>(Ab + (size_t)gm * g.lda + k0 + c8);
      int off = (r * 128 + c8 * 2) ^ ((r & 7) << 4);
      *reinterpret_cast<short8*>(reinterpret_cast<char*>(As) + off) = v;
    }
#pragma unroll
    for (int it = 0; it < BN / 32; ++it) {
      int idx = tid + it * 256, r = idx >> 3, c8 = (idx & 7) * 8;
      int gn = bx * BN + r;
      short8 v = *reinterpret_cast<const short8*>(Bb + (size_t)gn * g.ldb + k0 + c8);
      int off = (r * 128 + c8 * 2) ^ ((r & 7) << 4);
      *reinterpret_cast<short8*>(reinterpret_cast<char*>(Bs) + off) = v;
    }
    __syncthreads();
#pragma unroll
    for (int ks = 0; ks < 2; ++ks) {
      const int kb = (ks * 32 + lg * 8) * 2;
      short8 a[FM], b[FN];
#pragma unroll
      for (int fm = 0; fm < FM; ++fm) {
        int r = wm * WM + fm * 16 + lr;
        a[fm] = *reinterpret_cast<const short8*>(
            reinterpret_cast<const char*>(As) + ((r * 128 + kb) ^ ((r & 7) << 4)));
      }
#pragma unroll
      for (int fn = 0; fn < FN; ++fn) {
        int r = wn * WN + fn * 16 + lr;
        b[fn] = *reinterpret_cast<const short8*>(
            reinterpret_cast<const char*>(Bs) + ((r * 128 + kb) ^ ((r & 7) << 4)));
      }
#pragma unroll
      for (int fm = 0; fm < FM; ++fm)
#pragma unroll
        for (int fn = 0; fn < FN; ++fn)
          acc[fm][fn] = __builtin_amdgcn_mfma_f32_16x16x32_bf16(a[fm], b[fn], acc[fm][fn], 0, 0, 0);
    }
  }

  const int bg = (g.z0 + z) >> 3;
  const size_t zoff = (size_t)(z >> 3) * g.czo + (size_t)(z & 7) * g.czi;
#pragma unroll
  for (int fm = 0; fm < FM; ++fm) {
#pragma unroll
    for (int fn = 0; fn < FN; ++fn) {
#pragma unroll
      for (int r = 0; r < 4; ++r) {
        int m = by * BM + wm * WM + fm * 16 + lg * 4 + r;
        int n = bx * BN + wn * WN + fn * 16 + lr;
        if (m >= g.M) continue;
        float v = acc[fm][fn][r];
        size_t coff = zoff + (size_t)m * g.ldc + n;
        if (EPI == 0) {
          g.C[coff] = v;
        } else if (EPI == 1) {
          float rm = g.rowm[(size_t)bg * g.rms + m];
          float cm = g.colm[(size_t)bg * g.cms + n];
          g.C[coff] = (rm * cm < 0.5f) ? NEGV : v * SCALE;
        } else if (EPI == 2) {
          v += g.bias[n] + g.res[(size_t)m * g.ldr + n];
          g.C[coff] = v;
        } else if (EPI == 3) {
          v = gelu_f(v + g.bias[n]);
          g.Cb[coff] = __float2bfloat16(v);
        } else {
          g.Cb[coff] = __float2bfloat16(v);
        }
      }
    }
  }
}

// ---------------- weight transpose: f32 [K][N] -> bf16 [N][K] ----------------
__global__ __launch_bounds__(256)
void wtrans_kernel(const float* __restrict__ W, __hip_bfloat16* __restrict__ WT,
                   int K, int N) {
  __shared__ float t[64][65];
  const int n0 = blockIdx.x * 64, k0 = blockIdx.y * 64;
  const int tid = threadIdx.x;
#pragma unroll
  for (int it = 0; it < 4; ++it) {
    int idx = tid + it * 256, r = idx >> 4, f = idx & 15;
    float4 v = ldf4(W + (size_t)(k0 + r) * N + n0 + f * 4);
    t[r][f * 4 + 0] = v.x; t[r][f * 4 + 1] = v.y;
    t[r][f * 4 + 2] = v.z; t[r][f * 4 + 3] = v.w;
  }
  __syncthreads();
#pragma unroll
  for (int it = 0; it < 4; ++it) {
    int idx = tid + it * 256, r = idx >> 4, c4 = (idx & 15) * 4;
    __hip_bfloat16* op = WT + (size_t)(n0 + r) * K + k0 + c4;
#pragma unroll
    for (int e = 0; e < 4; ++e) op[e] = __float2bfloat16(t[c4 + e][r]);
  }
}

// ---------------- qkv split: hi/lo bf16 operand prep ----------------
// Q_SPLIT=true : q -> hi|lo [128] (qout), k -> hi [64] (kout)   (x tokens)
// Q_SPLIT=false: q -> hi [64] (qout), k -> hi|lo [128] (kout)   (k tokens)
template<bool Q_SPLIT>
__global__ __launch_bounds__(256)
void split_kernel(const float* __restrict__ qkv, __hip_bfloat16* __restrict__ qout,
                  __hip_bfloat16* __restrict__ kout, int T) {
  const int idx = blockIdx.x * 256 + threadIdx.x;     // B*T*128 items
  const int token = idx >> 7, c8 = (idx & 127) * 8;
  const int b = token / T, i = token - b * T;
  const float* p = qkv + (size_t)token * QLD + c8;
  float v[8];
  float4 a = ldf4(p), c = ldf4(p + 4);
  v[0]=a.x; v[1]=a.y; v[2]=a.z; v[3]=a.w; v[4]=c.x; v[5]=c.y; v[6]=c.z; v[7]=c.w;
  if (c8 < 512) {
    int h = c8 >> 6, d = c8 & 63;
    if (Q_SPLIT) {
      __hip_bfloat16* q = qout + ((size_t)((b * 8 + h) * T + i)) * 128 + d;
#pragma unroll
      for (int e = 0; e < 8; ++e) {
        __hip_bfloat16 hi = __float2bfloat16(v[e]);
        q[e] = hi;
        q[64 + e] = __float2bfloat16(v[e] - __bfloat162float(hi));
      }
    } else {
      __hip_bfloat16* q = qout + ((size_t)((b * 8 + h) * T + i)) * 64 + d;
#pragma unroll
      for (int e = 0; e < 8; ++e) q[e] = __float2bfloat16(v[e]);
    }
  } else {
    int cc = c8 - 512, h = cc >> 6, d = cc & 63;
    if (Q_SPLIT) {
      __hip_bfloat16* k = kout + ((size_t)((b * 8 + h) * T + i)) * 64 + d;
#pragma unroll
      for (int e = 0; e < 8; ++e) k[e] = __float2bfloat16(v[e]);
    } else {
      __hip_bfloat16* k = kout + ((size_t)((b * 8 + h) * T + i)) * 128 + d;
#pragma unroll
      for (int e = 0; e < 8; ++e) {
        __hip_bfloat16 hi = __float2bfloat16(v[e]);
        k[e] = hi;
        k[64 + e] = __float2bfloat16(v[e] - __bfloat162float(hi));
      }
    }
  }
}

// ---------------- v transpose: qkv v-part -> bf16 [bh][d][token] ----------------
__global__ __launch_bounds__(256)
void vtrans_kernel(const float* __restrict__ qkv, __hip_bfloat16* __restrict__ vT, int T) {
  __shared__ float t[64][65];
  const int bh = blockIdx.x, b = bh >> 3, h = bh & 7;
  const int i0 = blockIdx.y * 64;
  const int tid = threadIdx.x;
#pragma unroll
  for (int it = 0; it < 4; ++it) {
    int idx = tid + it * 256, r = idx >> 4, f = idx & 15;
    float4 v = ldf4(qkv + (size_t)(b * T + i0 + r) * QLD + 2 * Dd + h * 64 + f * 4);
    t[r][f * 4 + 0] = v.x; t[r][f * 4 + 1] = v.y;
    t[r][f * 4 + 2] = v.z; t[r][f * 4 + 3] = v.w;
  }
  __syncthreads();
#pragma unroll
  for (int it = 0; it < 4; ++it) {
    int idx = tid + it * 256, d = idx >> 4, c4 = (idx & 15) * 4;
    __hip_bfloat16* op = vT + (size_t)(bh * 64 + d) * T + i0 + c4;
#pragma unroll
    for (int e = 0; e < 4; ++e) op[e] = __float2bfloat16(t[c4 + e][d]);
  }
}

// ---------------- x-path softmax (dual e1/e24) + rd + atten write ----------------
// grid (Nn/16, CHUNK); S layout [zloc][i][j], 16 bh per chunk.
__global__ __launch_bounds__(256)
void softmax_x_kernel(const float* __restrict__ S, const float* __restrict__ rd,
                      __hip_bfloat16* __restrict__ P1, float* __restrict__ atten, int z0) {
  __shared__ float rd_s[MK][17];
  __shared__ float e24_s[16][261];
  const int tid = threadIdx.x, l = tid & 63, w = tid >> 6;
  const int zloc = blockIdx.y, bh = z0 + zloc, b = bh >> 3;
  const int i0 = blockIdx.x * 16;
  // rd tile: 256 j x 16 i
#pragma unroll
  for (int it = 0; it < 4; ++it) {
    int idx = tid + it * 256, j = idx >> 2, f = idx & 3;
    float4 v = ldf4(rd + (size_t)(b * MK + j) * Nn + i0 + f * 4);
    rd_s[j][f * 4 + 0] = v.x; rd_s[j][f * 4 + 1] = v.y;
    rd_s[j][f * 4 + 2] = v.z; rd_s[j][f * 4 + 3] = v.w;
  }
  __syncthreads();
#pragma unroll
  for (int rr = 0; rr < 4; ++rr) {
    const int r = w * 4 + rr;
    const int i = i0 + r;
    const float* sp = S + ((size_t)zloc * Nn + i) * MK;
    float d0 = sp[l], d1 = sp[l + 64], d2 = sp[l + 128], d3 = sp[l + 192];
    float mx = fmaxf(fmaxf(d0, d1), fmaxf(d2, d3));
    mx = waveMax(mx);
    float e10 = __expf(d0 - mx), e11 = __expf(d1 - mx), e12 = __expf(d2 - mx), e13 = __expf(d3 - mx);
    float f0 = __expf(24.f * (d0 - mx)), f1 = __expf(24.f * (d1 - mx));
    float f2 = __expf(24.f * (d2 - mx)), f3 = __expf(24.f * (d3 - mx));
    float s1 = waveSum(e10 + e11 + e12 + e13);
    float s24 = waveSum(f0 + f1 + f2 + f3);
    const float i1 = 1.f / s1, i24 = 1.f / s24;
    __hip_bfloat16* pp = P1 + ((size_t)bh * Nn + i) * MK;
    float r0 = rd_s[l][r], r1 = rd_s[l + 64][r], r2 = rd_s[l + 128][r], r3 = rd_s[l + 192][r];
    pp[l]       = __float2bfloat16(e10 * i1 * r0);
    pp[l + 64]  = __float2bfloat16(e11 * i1 * r1);
    pp[l + 128] = __float2bfloat16(e12 * i1 * r2);
    pp[l + 192] = __float2bfloat16(e13 * i1 * r3);
    e24_s[r][l]       = f0 * i24 * r0;
    e24_s[r][l + 64]  = f1 * i24 * r1;
    e24_s[r][l + 128] = f2 * i24 * r2;
    e24_s[r][l + 192] = f3 * i24 * r3;
  }
  __syncthreads();
  // atten[bh][j][i0..i0+16) ; lanes: 4 j x 16 i per instruction
  const int iL = l & 15, jg = l >> 4;
#pragma unroll
  for (int jj = 0; jj < 16; ++jj) {
    int j = w * 64 + jj * 4 + jg;
    atten[((size_t)bh * MK + j) * Nn + i0 + iL] = e24_s[iL][j];
  }
}

// ---------------- k-path softmax + rd ----------------
// grid (MK, CHUNK); S layout [zloc][j][i]
__global__ __launch_bounds__(256)
void softmax_k_kernel(const float* __restrict__ S, const float* __restrict__ rd,
                      __hip_bfloat16* __restrict__ P2, int z0) {
  __shared__ float red8[8];
  const int tid = threadIdx.x;
  const int j = blockIdx.x, zloc = blockIdx.y, bh = z0 + zloc, b = bh >> 3;
  const float* row = S + ((size_t)zloc * MK + j) * Nn;
  float d[8];
  float lm = -3.4e38f;
#pragma unroll
  for (int c = 0; c < 8; ++c) { d[c] = row[c * 256 + tid]; lm = fmaxf(lm, d[c]); }
  const float mx = blockMax256(lm, red8);
  float ls = 0.f;
#pragma unroll
  for (int c = 0; c < 8; ++c) { d[c] = __expf(d[c] - mx); ls += d[c]; }
  const float s = blockSum256(ls, red8);
  const float inv = 1.f / s;
  const float* rp = rd + (size_t)(b * MK + j) * Nn;
  __hip_bfloat16* pp = P2 + ((size_t)bh * MK + j) * Nn;
#pragma unroll
  for (int c = 0; c < 8; ++c)
    pp[c * 256 + tid] = __float2bfloat16(d[c] * inv * rp[c * 256 + tid]);
}

// ------------- cls-token attention: grid B*H, block 256 -------------
__global__ __launch_bounds__(256)
void attn_c_kernel(const float* __restrict__ cqkv, const float* __restrict__ kqkv,
                   const float* __restrict__ mask, const float* __restrict__ kmask,
                   float* __restrict__ c_pre) {
  __shared__ __align__(16) float kv_s[MK][DH];
  __shared__ __align__(16) float q_s[DH];
  __shared__ float pbuf[MK];
  __shared__ float red8[8];
  __shared__ float redpv[4][DH];
  const int tid = threadIdx.x;
  const int bh = blockIdx.x, b = bh >> 3, h = bh & 7;
  const float* vp = kqkv + ((size_t)(b * MK + tid)) * QLD + 2 * Dd + h * DH;
#pragma unroll
  for (int q4 = 0; q4 < 16; ++q4)
    *reinterpret_cast<float4*>(&kv_s[tid][q4 * 4]) = ldf4(vp + q4 * 4);
  if (tid < DH) q_s[tid] = cqkv[(size_t)b * QLD + h * DH + tid];
  __syncthreads();
  const float* kp = kqkv + ((size_t)(b * MK + tid)) * QLD + Dd + h * DH;
  float dot = 0.f;
#pragma unroll
  for (int q4 = 0; q4 < 16; ++q4) {
    float4 kv4 = ldf4(kp + q4 * 4);
    float4 qv = ldf4(&q_s[q4 * 4]);
    dot = fmaf(qv.x, kv4.x, dot);
    dot = fmaf(qv.y, kv4.y, dot);
    dot = fmaf(qv.z, kv4.z, dot);
    dot = fmaf(qv.w, kv4.w, dot);
  }
  const float dm = (mask[(size_t)b * Nn] * kmask[b * MK + tid] < 0.5f) ? NEGV : dot * SCALE;
  const float mx = blockMax256(dm, red8);
  const float e = __expf(dm - mx);
  const float s = blockSum256(e, red8);
  pbuf[tid] = e / s;
  __syncthreads();
  const int d = tid & 63, g = tid >> 6;
  float acc = 0.f;
#pragma unroll 8
  for (int jj = 0; jj < 64; ++jj)
    acc = fmaf(pbuf[g * 64 + jj], kv_s[g * 64 + jj][d], acc);
  redpv[g][d] = acc;
  __syncthreads();
  if (tid < DH)
    c_pre[(size_t)b * Dd + h * DH + tid] =
        redpv[0][tid] + redpv[1][tid] + redpv[2][tid] + redpv[3][tid];
}

// ------------- output writers (float32 outputs) -------------
__global__ void kreps_kernel(const float* __restrict__ kx, const float* __restrict__ kmask,
                             float* __restrict__ o) {
  const int idx = blockIdx.x * 256 + threadIdx.x;
  const int bj = idx >> 9;
  const float keep = (kmask[bj] >= 0.5f) ? 1.f : 0.f;
  o[idx] = kx[idx] * keep;
}
__global__ void cout_kernel(const float* __restrict__ c_s, float* __restrict__ o) {
  const int idx = blockIdx.x * 256 + threadIdx.x;
  o[idx] = c_s[idx];
}

// ------------- host-side wrappers -------------
template<bool BIAS_, bool GELU_, bool RES_>
static void gemm_f32(const float* A, const float* Bm, const float* bias, const float* R,
                     float* C, int M, int K, int N, hipStream_t s) {
  dim3 grid(N / 64, (M + 63) / 64);
  gemm_kernel<BIAS_, GELU_, RES_><<<grid, 256, 0, s>>>(A, Bm, bias, R, C, M, K, N);
}

static GArgs ga_base() { GArgs g = {}; return g; }

extern "C" void kernel_launch(void* const* d_in, const int* in_sizes, int n_in,
                              void* d_out, int out_size, void* d_ws, size_t ws_size,
                              hipStream_t stream) {
  (void)in_sizes; (void)n_in; (void)out_size; (void)ws_size;
  const float* x_in  = (const float*)d_in[0];
  const float* kx_in = (const float*)d_in[1];
  const float* rd    = (const float*)d_in[2];
  const float* c_in  = (const float*)d_in[3];
  const float* mask  = (const float*)d_in[4];
  const float* kmask = (const float*)d_in[5];
  const float* ln1g  = (const float*)d_in[6];
  const float* ln1b  = (const float*)d_in[7];
  const float* Wqkv  = (const float*)d_in[8];
  const float* Woutw = (const float*)d_in[9];
  const float* boutw = (const float*)d_in[10];
  const float* ln2g  = (const float*)d_in[11];
  const float* ln2b  = (const float*)d_in[12];
  const float* W1    = (const float*)d_in[13];
  const float* b1    = (const float*)d_in[14];
  const float* W2    = (const float*)d_in[15];
  const float* b2    = (const float*)d_in[16];
  float* out = (float*)d_out;

  float* ws = (float*)d_ws;
  size_t off = 0;
  auto alloc = [&](size_t n) { float* p = ws + off; off += (n + 15) & ~(size_t)15; return p; };
  float* x_s   = alloc((size_t)Bb * Nn * Dd);
  float* xn    = alloc((size_t)Bb * Nn * Dd);
  float* xn_bf_f = alloc((size_t)Bb * Nn * Dd / 2);
  float* kx_s  = alloc((size_t)Bb * MK * Dd);
  float* kxn   = alloc((size_t)Bb * MK * Dd);
  float* kxn_bf_f = alloc((size_t)Bb * MK * Dd / 2);
  float* c_s   = alloc((size_t)Bb * Dd);
  float* cn    = alloc((size_t)Bb * Dd);
  float* cqkv  = alloc((size_t)Bb * QLD);
  float* chid  = alloc((size_t)Bb * MLPD);
  float* c_pre = alloc((size_t)Bb * Dd);
  float* tqkv  = alloc((size_t)Bb * Nn * QLD);       // hosts P / hid later
  float* kqkv  = alloc((size_t)Bb * MK * QLD);       // hosts hid_kx later
  float* S     = alloc((size_t)16 * Nn * MK);        // score scratch, 16 bh per chunk
  float* tq_s_f  = alloc((size_t)32 * Nn * 128 / 2);
  float* kk_s_f  = alloc((size_t)32 * MK * 128 / 2);
  float* tk_hi_f = alloc((size_t)32 * Nn * 64 / 2);
  float* kq_hi_f = alloc((size_t)32 * MK * 64 / 2);
  float* tvT_f   = alloc((size_t)32 * 64 * Nn / 2);
  float* kvT_f   = alloc((size_t)32 * 64 * MK / 2);
  float* xpre_f  = alloc((size_t)Bb * Nn * Dd / 2);
  float* kxpre_f = alloc((size_t)Bb * MK * Dd / 2);
  float* WqkvT_f = alloc((size_t)QLD * Dd / 2);
  float* WoutT_f = alloc((size_t)Dd * Dd / 2);
  float* W1T_f   = alloc((size_t)MLPD * Dd / 2);
  float* W2T_f   = alloc((size_t)Dd * MLPD / 2);

  __hip_bfloat16* xn_bf  = (__hip_bfloat16*)xn_bf_f;
  __hip_bfloat16* kxn_bf = (__hip_bfloat16*)kxn_bf_f;
  __hip_bfloat16* tq_s   = (__hip_bfloat16*)tq_s_f;
  __hip_bfloat16* kk_s   = (__hip_bfloat16*)kk_s_f;
  __hip_bfloat16* tk_hi  = (__hip_bfloat16*)tk_hi_f;
  __hip_bfloat16* kq_hi  = (__hip_bfloat16*)kq_hi_f;
  __hip_bfloat16* tvT    = (__hip_bfloat16*)tvT_f;
  __hip_bfloat16* kvT    = (__hip_bfloat16*)kvT_f;
  __hip_bfloat16* x_pre  = (__hip_bfloat16*)xpre_f;
  __hip_bfloat16* kx_pre = (__hip_bfloat16*)kxpre_f;
  __hip_bfloat16* WqkvT  = (__hip_bfloat16*)WqkvT_f;
  __hip_bfloat16* WoutT  = (__hip_bfloat16*)WoutT_f;
  __hip_bfloat16* W1T    = (__hip_bfloat16*)W1T_f;
  __hip_bfloat16* W2T    = (__hip_bfloat16*)W2T_f;
  __hip_bfloat16* Pbuf   = (__hip_bfloat16*)tqkv;    // P1 / P2 overlay
  __hip_bfloat16* hid    = (__hip_bfloat16*)tqkv;    // FF hidden overlay
  __hip_bfloat16* hid_kx = (__hip_bfloat16*)kqkv;

  const size_t CL_OFF = (size_t)2 * Bb * MK * Dd;
  const size_t AT_OFF = CL_OFF + (size_t)Bb * Dd;

  for (int l = 0; l < 2; ++l) {
    const float* xp  = (l == 0) ? x_in  : x_s;
    const float* kxp = (l == 0) ? kx_in : kx_s;
    const float* cp  = (l == 0) ? c_in  : c_s;
    ln_kernel<<<Bb * Nn, 64, 0, stream>>>(xp,  ln1g + l * Dd, ln1b + l * Dd, xn,  xn_bf);
    ln_kernel<<<Bb * MK, 64, 0, stream>>>(kxp, ln1g + l * Dd, ln1b + l * Dd, kxn, kxn_bf);
    ln_kernel<<<Bb,      64, 0, stream>>>(cp,  ln1g + l * Dd, ln1b + l * Dd, cn,  nullptr);

    const float* Wq = Wqkv + (size_t)l * Dd * QLD;
    const float* Wo = Woutw + (size_t)l * Dd * Dd;
    const float* bo = boutw + (size_t)l * Dd;
    const float* W1l = W1 + (size_t)l * Dd * MLPD;
    const float* b1l = b1 + (size_t)l * MLPD;
    const float* W2l = W2 + (size_t)l * MLPD * Dd;
    const float* b2l = b2 + (size_t)l * Dd;
    wtrans_kernel<<<dim3(QLD / 64, Dd / 64), 256, 0, stream>>>(Wq, WqkvT, Dd, QLD);
    wtrans_kernel<<<dim3(Dd / 64, Dd / 64), 256, 0, stream>>>(Wo, WoutT, Dd, Dd);
    wtrans_kernel<<<dim3(MLPD / 64, Dd / 64), 256, 0, stream>>>(W1l, W1T, Dd, MLPD);
    wtrans_kernel<<<dim3(Dd / 64, MLPD / 64), 256, 0, stream>>>(W2l, W2T, MLPD, Dd);

    // QKV
    {
      GArgs g = ga_base();
      g.A = (const short*)xn_bf; g.lda = Dd;
      g.Bt = (const short*)WqkvT; g.ldb = Dd;
      g.C = tqkv; g.ldc = QLD;
      g.M = Bb * Nn; g.N = QLD; g.K = Dd;
      mgemm<128, 128, 0><<<dim3(QLD / 128, Bb * Nn / 128, 1), 256, 0, stream>>>(g);
      g.A = (const short*)kxn_bf; g.C = kqkv; g.M = Bb * MK;
      mgemm<128, 128, 0><<<dim3(QLD / 128, Bb * MK / 128, 1), 256, 0, stream>>>(g);
    }
    gemm_f32<false, false, false>(cn, Wq, nullptr, nullptr, cqkv, Bb, Dd, QLD, stream);

    split_kernel<true><<<(Bb * Nn * 128) / 256, 256, 0, stream>>>(tqkv, tq_s, tk_hi, Nn);
    split_kernel<false><<<(Bb * MK * 128) / 256, 256, 0, stream>>>(kqkv, kq_hi, kk_s, MK);
    vtrans_kernel<<<dim3(32, Nn / 64), 256, 0, stream>>>(tqkv, tvT, Nn);
    vtrans_kernel<<<dim3(32, MK / 64), 256, 0, stream>>>(kqkv, kvT, MK);

    // ---- x-path attention ----
    for (int ch = 0; ch < 2; ++ch) {
      GArgs g = ga_base();
      g.A = (const short*)(tq_s + (size_t)ch * 16 * Nn * 128); g.asb = (long)Nn * 128; g.lda = 128;
      g.Bt = (const short*)(kk_s + (size_t)ch * 16 * MK * 128); g.bsb = (long)MK * 128; g.ldb = 128;
      g.C = S; g.czi = (long)Nn * MK; g.czo = 8L * Nn * MK; g.ldc = MK;
      g.rowm = mask; g.rms = Nn; g.colm = kmask; g.cms = MK;
      g.z0 = ch * 16; g.M = Nn; g.N = MK; g.K = 128;
      mgemm<128, 128, 1><<<dim3(MK / 128, Nn / 128, 16), 256, 0, stream>>>(g);
      softmax_x_kernel<<<dim3(Nn / 16, 16), 256, 0, stream>>>(
          S, rd, Pbuf, out + AT_OFF + (size_t)l * 32 * MK * Nn, ch * 16);
    }
    {
      GArgs g = ga_base();
      g.A = (const short*)Pbuf; g.asb = (long)Nn * MK; g.lda = MK;
      g.Bt = (const short*)kvT; g.bsb = (long)64 * MK; g.ldb = MK;
      g.Cb = x_pre; g.czo = (long)Nn * Dd; g.czi = 64; g.ldc = Dd;
      g.M = Nn; g.N = 64; g.K = MK;
      mgemm<128, 64, 4><<<dim3(1, Nn / 128, 32), 256, 0, stream>>>(g);
    }
    // ---- k-path attention ----
    for (int ch = 0; ch < 2; ++ch) {
      GArgs g = ga_base();
      g.A = (const short*)(kq_hi + (size_t)ch * 16 * MK * 64); g.asb = (long)MK * 64; g.lda = 64;
      g.Bt = (const short*)(tk_hi + (size_t)ch * 16 * Nn * 64); g.bsb = (long)Nn * 64; g.ldb = 64;
      g.C = S; g.czi = (long)MK * Nn; g.czo = 8L * MK * Nn; g.ldc = Nn;
      g.rowm = kmask; g.rms = MK; g.colm = mask; g.cms = Nn;
      g.z0 = ch * 16; g.M = MK; g.N = Nn; g.K = 64;
      mgemm<128, 128, 1><<<dim3(Nn / 128, MK / 128, 16), 256, 0, stream>>>(g);
      softmax_k_kernel<<<dim3(MK, 16), 256, 0, stream>>>(S, rd, Pbuf, ch * 16);
    }
    {
      GArgs g = ga_base();
      g.A = (const short*)Pbuf; g.asb = (long)MK * Nn; g.lda = Nn;
      g.Bt = (const short*)tvT; g.bsb = (long)64 * Nn; g.ldb = Nn;
      g.Cb = kx_pre; g.czo = (long)MK * Dd; g.czi = 64; g.ldc = Dd;
      g.M = MK; g.N = 64; g.K = Nn;
      mgemm<128, 64, 4><<<dim3(1, MK / 128, 32), 256, 0, stream>>>(g);
    }
    attn_c_kernel<<<Bb * Hh, 256, 0, stream>>>(cqkv, kqkv, mask, kmask, c_pre);

    // ---- Wout + residual ----
    {
      GArgs g = ga_base();
      g.A = (const short*)x_pre; g.lda = Dd;
      g.Bt = (const short*)WoutT; g.ldb = Dd;
      g.C = x_s; g.ldc = Dd; g.bias = bo; g.res = xn; g.ldr = Dd;
      g.M = Bb * Nn; g.N = Dd; g.K = Dd;
      mgemm<128, 128, 2><<<dim3(Dd / 128, Bb * Nn / 128, 1), 256, 0, stream>>>(g);
      g.A = (const short*)kx_pre; g.C = kx_s; g.res = kxn; g.M = Bb * MK;
      mgemm<128, 128, 2><<<dim3(Dd / 128, Bb * MK / 128, 1), 256, 0, stream>>>(g);
    }
    gemm_f32<true, false, true>(c_pre, Wo, bo, cn, c_s, Bb, Dd, Dd, stream);

    // ---- FF x ----
    ln_kernel<<<Bb * Nn, 64, 0, stream>>>(x_s, ln2g + l * Dd, ln2b + l * Dd, xn, xn_bf);
    {
      GArgs g = ga_base();
      g.A = (const short*)xn_bf; g.lda = Dd;
      g.Bt = (const short*)W1T; g.ldb = Dd;
      g.Cb = hid; g.ldc = MLPD; g.bias = b1l;
      g.M = Bb * Nn; g.N = MLPD; g.K = Dd;
      mgemm<128, 128, 3><<<dim3(MLPD / 128, Bb * Nn / 128, 1), 256, 0, stream>>>(g);
      GArgs h = ga_base();
      h.A = (const short*)hid; h.lda = MLPD;
      h.Bt = (const short*)W2T; h.ldb = MLPD;
      h.C = x_s; h.ldc = Dd; h.bias = b2l; h.res = x_s; h.ldr = Dd;
      h.M = Bb * Nn; h.N = Dd; h.K = MLPD;
      mgemm<128, 128, 2><<<dim3(Dd / 128, Bb * Nn / 128, 1), 256, 0, stream>>>(h);
    }
    // ---- FF kx ----
    ln_kernel<<<Bb * MK, 64, 0, stream>>>(kx_s, ln2g + l * Dd, ln2b + l * Dd, kxn, kxn_bf);
    {
      GArgs g = ga_base();
      g.A = (const short*)kxn_bf; g.lda = Dd;
      g.Bt = (const short*)W1T; g.ldb = Dd;
      g.Cb = hid_kx; g.ldc = MLPD; g.bias = b1l;
      g.M = Bb * MK; g.N = MLPD; g.K = Dd;
      mgemm<128, 128, 3><<<dim3(MLPD / 128, Bb * MK / 128, 1), 256, 0, stream>>>(g);
      GArgs h = ga_base();
      h.A = (const short*)hid_kx; h.lda = MLPD;
      h.Bt = (const short*)W2T; h.ldb = MLPD;
      h.C = kx_s; h.ldc = Dd; h.bias = b2l; h.res = kx_s; h.ldr = Dd;
      h.M = Bb * MK; h.N = Dd; h.K = MLPD;
      mgemm<128, 128, 2><<<dim3(Dd / 128, Bb * MK / 128, 1), 256, 0, stream>>>(h);
    }
    // ---- FF c (f32 path) ----
    ln_kernel<<<Bb, 64, 0, stream>>>(c_s, ln2g + l * Dd, ln2b + l * Dd, cn, nullptr);
    gemm_f32<true, true,  false>(cn,   W1l, b1l, nullptr, chid, Bb, Dd,   MLPD, stream);
    gemm_f32<true, false, true >(chid, W2l, b2l, c_s,     c_s,  Bb, MLPD, Dd,   stream);

    kreps_kernel<<<(Bb * MK * Dd) / 256, 256, 0, stream>>>(kx_s, kmask,
                                                           out + (size_t)l * Bb * MK * Dd);
  }
  cout_kernel<<<(Bb * Dd) / 256, 256, 0, stream>>>(c_s, out + CL_OFF);
}

// Round 4
// 1740.352 us; speedup vs baseline: 2.5784x; 1.0032x over previous
//
#include <hip/hip_runtime.h>
#include <hip/hip_bf16.h>
#include <cstddef>

#define DEV __device__ __forceinline__

constexpr int Bb  = 4;
constexpr int Nn  = 2048;
constexpr int MK  = 256;
constexpr int Dd  = 512;
constexpr int Hh  = 8;
constexpr int DH  = 64;
constexpr int QLD = 1536;   // qkv row stride (3*512)
constexpr int MLPD = 2048;
constexpr float SCALE = 0.125f;   // 64^-0.5
constexpr float NEGV  = -1e9f;

typedef __attribute__((ext_vector_type(8))) short short8;
typedef __attribute__((ext_vector_type(4))) float f32x4;

DEV float4 ldf4(const float* p) { return *reinterpret_cast<const float4*>(p); }

DEV float waveMax(float v) {
#pragma unroll
  for (int o = 32; o; o >>= 1) v = fmaxf(v, __shfl_xor(v, o));
  return v;
}
DEV float waveSum(float v) {
#pragma unroll
  for (int o = 32; o; o >>= 1) v += __shfl_xor(v, o);
  return v;
}
DEV float blockMax256(float v, float* red) {
  v = waveMax(v);
  __syncthreads();
  if ((threadIdx.x & 63) == 0) red[threadIdx.x >> 6] = v;
  __syncthreads();
  return fmaxf(fmaxf(red[0], red[1]), fmaxf(red[2], red[3]));
}
DEV float blockSum256(float v, float* red) {
  v = waveSum(v);
  __syncthreads();
  if ((threadIdx.x & 63) == 0) red[threadIdx.x >> 6] = v;
  __syncthreads();
  return red[0] + red[1] + red[2] + red[3];
}
DEV float gelu_f(float x) { return 0.5f * x * (1.f + erff(x * 0.70710678118654752f)); }

// ---------------- LayerNorm: one wave per 512-float row, dual f32+bf16 out ----------------
__global__ __launch_bounds__(64)
void ln_kernel(const float* __restrict__ in, const float* __restrict__ gw,
               const float* __restrict__ bw, float* __restrict__ out,
               __hip_bfloat16* __restrict__ outb) {
  const int row = blockIdx.x;
  const int t = threadIdx.x;
  const float* p = in + (size_t)row * Dd + t * 8;
  float4 v0 = ldf4(p), v1 = ldf4(p + 4);
  float s = v0.x + v0.y + v0.z + v0.w + v1.x + v1.y + v1.z + v1.w;
  float q = v0.x*v0.x + v0.y*v0.y + v0.z*v0.z + v0.w*v0.w
          + v1.x*v1.x + v1.y*v1.y + v1.z*v1.z + v1.w*v1.w;
  s = waveSum(s); q = waveSum(q);
  const float mu = s * (1.f / Dd);
  const float rstd = rsqrtf(fmaxf(q * (1.f / Dd) - mu * mu, 0.f) + 1e-5f);
  float4 g0 = ldf4(gw + t * 8), g1 = ldf4(gw + t * 8 + 4);
  float4 b0 = ldf4(bw + t * 8), b1 = ldf4(bw + t * 8 + 4);
  float o[8];
  o[0] = (v0.x - mu) * rstd * g0.x + b0.x;
  o[1] = (v0.y - mu) * rstd * g0.y + b0.y;
  o[2] = (v0.z - mu) * rstd * g0.z + b0.z;
  o[3] = (v0.w - mu) * rstd * g0.w + b0.w;
  o[4] = (v1.x - mu) * rstd * g1.x + b1.x;
  o[5] = (v1.y - mu) * rstd * g1.y + b1.y;
  o[6] = (v1.z - mu) * rstd * g1.z + b1.z;
  o[7] = (v1.w - mu) * rstd * g1.w + b1.w;
  float* op = out + (size_t)row * Dd + t * 8;
  *reinterpret_cast<float4*>(op)     = make_float4(o[0], o[1], o[2], o[3]);
  *reinterpret_cast<float4*>(op + 4) = make_float4(o[4], o[5], o[6], o[7]);
  if (outb) {
    __hip_bfloat16* ob = outb + (size_t)row * Dd + t * 8;
#pragma unroll
    for (int e = 0; e < 8; ++e) ob[e] = __float2bfloat16(o[e]);
  }
}

// ---------------- cls-path small-M GEMV: C[4][N] = A[4][K] @ W[K][N] ----------------
// grid N/256, block 256. One thread per output column; A staged in LDS (broadcast reads).
template<bool BIAS_, bool GELU_, bool RES_>
__global__ __launch_bounds__(256)
void gemv4_kernel(const float* __restrict__ A, const float* __restrict__ W,
                  const float* __restrict__ bias, const float* __restrict__ R,
                  float* __restrict__ C, int K, int N) {
  __shared__ float As[4 * 2048];      // max K = 2048
  const int tid = threadIdx.x;
  for (int i = tid * 4; i < 4 * K; i += 1024)
    *reinterpret_cast<float4*>(&As[i]) = ldf4(A + i);
  __syncthreads();
  const int col = blockIdx.x * 256 + tid;
  const float* wp = W + col;
  float a0 = 0.f, a1 = 0.f, a2 = 0.f, a3 = 0.f;
#pragma unroll 8
  for (int k = 0; k < K; ++k) {
    float w = wp[(size_t)k * N];
    a0 = fmaf(As[k], w, a0);
    a1 = fmaf(As[K + k], w, a1);
    a2 = fmaf(As[2 * K + k], w, a2);
    a3 = fmaf(As[3 * K + k], w, a3);
  }
  float acc[4] = {a0, a1, a2, a3};
  const float bb = BIAS_ ? bias[col] : 0.f;
#pragma unroll
  for (int r = 0; r < 4; ++r) {
    float v = acc[r] + bb;
    if (GELU_) v = gelu_f(v);
    if (RES_) v += R[(size_t)r * N + col];
    C[(size_t)r * N + col] = v;
  }
}

// ---------------- bf16 MFMA GEMM ----------------
// C[M,N] = A[M,K] @ Bt[N,K]^T, batched over blockIdx.z. 256 threads.
// EPI: 0 = f32 write; 1 = mask+scale f32 (scores); 2 = +bias +res f32;
//      3 = +bias, gelu, bf16 write; 4 = bf16 write.
struct GArgs {
  const short* A;  long asb; int lda;
  const short* Bt; long bsb; int ldb;
  float* C; __hip_bfloat16* Cb;
  long czo, czi; int ldc;
  const float* bias;
  const float* res; int ldr;
  const float* rowm; int rms;
  const float* colm; int cms;
  int z0, M, N, K;
};

template<int BM, int BN, int EPI>
__global__ __launch_bounds__(256)
void mgemm(GArgs g) {
  constexpr int WMW = (BN >= 128) ? 2 : 4;
  constexpr int WNW = 4 / WMW;
  constexpr int WM = BM / WMW, WN = BN / WNW;
  constexpr int FM = WM / 16, FN = WN / 16;
  __shared__ short As[BM * 64];
  __shared__ short Bs[BN * 64];
  const int tid = threadIdx.x, l = tid & 63, w = tid >> 6;
  const int wm = (WNW == 2) ? (w >> 1) : w;
  const int wn = (WNW == 2) ? (w & 1) : 0;
  const int bx = blockIdx.x, by = blockIdx.y, z = blockIdx.z;
  const short* Ab = g.A + (size_t)z * g.asb;
  const short* Bb = g.Bt + (size_t)z * g.bsb;
  f32x4 acc[FM][FN] = {};
  const int lr = l & 15, lg = l >> 4;

  for (int k0 = 0; k0 < g.K; k0 += 64) {
    __syncthreads();
#pragma unroll
    for (int it = 0; it < BM / 32; ++it) {
      int idx = tid + it * 256, r = idx >> 3, c8 = (idx & 7) * 8;
      int gm = by * BM + r;
      short8 v = {};
      if (gm < g.M) v = *reinterpret_cast<const short8*>(Ab + (size_t)gm * g.lda + k0 + c8);
      int off = (r * 128 + c8 * 2) ^ ((r & 7) << 4);
      *reinterpret_cast<short8*>(reinterpret_cast<char*>(As) + off) = v;
    }
#pragma unroll
    for (int it = 0; it < BN / 32; ++it) {
      int idx = tid + it * 256, r = idx >> 3, c8 = (idx & 7) * 8;
      int gn = bx * BN + r;
      short8 v = *reinterpret_cast<const short8*>(Bb + (size_t)gn * g.ldb + k0 + c8);
      int off = (r * 128 + c8 * 2) ^ ((r & 7) << 4);
      *reinterpret_cast<short8*>(reinterpret_cast<char*>(Bs) + off) = v;
    }
    __syncthreads();
#pragma unroll
    for (int ks = 0; ks < 2; ++ks) {
      const int kb = (ks * 32 + lg * 8) * 2;
      short8 a[FM], b[FN];
#pragma unroll
      for (int fm = 0; fm < FM; ++fm) {
        int r = wm * WM + fm * 16 + lr;
        a[fm] = *reinterpret_cast<const short8*>(
            reinterpret_cast<const char*>(As) + ((r * 128 + kb) ^ ((r & 7) << 4)));
      }
#pragma unroll
      for (int fn = 0; fn < FN; ++fn) {
        int r = wn * WN + fn * 16 + lr;
        b[fn] = *reinterpret_cast<const short8*>(
            reinterpret_cast<const char*>(Bs) + ((r * 128 + kb) ^ ((r & 7) << 4)));
      }
#pragma unroll
      for (int fm = 0; fm < FM; ++fm)
#pragma unroll
        for (int fn = 0; fn < FN; ++fn)
          acc[fm][fn] = __builtin_amdgcn_mfma_f32_16x16x32_bf16(a[fm], b[fn], acc[fm][fn], 0, 0, 0);
    }
  }

  const int bg = (g.z0 + z) >> 3;
  const size_t zoff = (size_t)(z >> 3) * g.czo + (size_t)(z & 7) * g.czi;
#pragma unroll
  for (int fm = 0; fm < FM; ++fm) {
#pragma unroll
    for (int fn = 0; fn < FN; ++fn) {
#pragma unroll
      for (int r = 0; r < 4; ++r) {
        int m = by * BM + wm * WM + fm * 16 + lg * 4 + r;
        int n = bx * BN + wn * WN + fn * 16 + lr;
        if (m >= g.M) continue;
        float v = acc[fm][fn][r];
        size_t coff = zoff + (size_t)m * g.ldc + n;
        if (EPI == 0) {
          g.C[coff] = v;
        } else if (EPI == 1) {
          float rm = g.rowm[(size_t)bg * g.rms + m];
          float cm = g.colm[(size_t)bg * g.cms + n];
          g.C[coff] = (rm * cm < 0.5f) ? NEGV : v * SCALE;
        } else if (EPI == 2) {
          v += g.bias[n] + g.res[(size_t)m * g.ldr + n];
          g.C[coff] = v;
        } else if (EPI == 3) {
          v = gelu_f(v + g.bias[n]);
          g.Cb[coff] = __float2bfloat16(v);
        } else {
          g.Cb[coff] = __float2bfloat16(v);
        }
      }
    }
  }
}

// ---------------- weight transpose: f32 [K][N] -> bf16 [N][K] ----------------
__global__ __launch_bounds__(256)
void wtrans_kernel(const float* __restrict__ W, __hip_bfloat16* __restrict__ WT,
                   int K, int N) {
  __shared__ float t[64][65];
  const int n0 = blockIdx.x * 64, k0 = blockIdx.y * 64;
  const int tid = threadIdx.x;
#pragma unroll
  for (int it = 0; it < 4; ++it) {
    int idx = tid + it * 256, r = idx >> 4, f = idx & 15;
    float4 v = ldf4(W + (size_t)(k0 + r) * N + n0 + f * 4);
    t[r][f * 4 + 0] = v.x; t[r][f * 4 + 1] = v.y;
    t[r][f * 4 + 2] = v.z; t[r][f * 4 + 3] = v.w;
  }
  __syncthreads();
#pragma unroll
  for (int it = 0; it < 4; ++it) {
    int idx = tid + it * 256, r = idx >> 4, c4 = (idx & 15) * 4;
    __hip_bfloat16* op = WT + (size_t)(n0 + r) * K + k0 + c4;
#pragma unroll
    for (int e = 0; e < 4; ++e) op[e] = __float2bfloat16(t[c4 + e][r]);
  }
}

// ---------------- qkv split: hi/lo bf16 operand prep ----------------
// Q_SPLIT=true : q -> hi|lo [128] (qout), k -> hi [64] (kout)   (x tokens)
// Q_SPLIT=false: q -> hi [64] (qout), k -> hi|lo [128] (kout)   (k tokens)
template<bool Q_SPLIT>
__global__ __launch_bounds__(256)
void split_kernel(const float* __restrict__ qkv, __hip_bfloat16* __restrict__ qout,
                  __hip_bfloat16* __restrict__ kout, int T) {
  const int idx = blockIdx.x * 256 + threadIdx.x;     // B*T*128 items
  const int token = idx >> 7, c8 = (idx & 127) * 8;
  const int b = token / T, i = token - b * T;
  const float* p = qkv + (size_t)token * QLD + c8;
  float v[8];
  float4 a = ldf4(p), c = ldf4(p + 4);
  v[0]=a.x; v[1]=a.y; v[2]=a.z; v[3]=a.w; v[4]=c.x; v[5]=c.y; v[6]=c.z; v[7]=c.w;
  if (c8 < 512) {
    int h = c8 >> 6, d = c8 & 63;
    if (Q_SPLIT) {
      __hip_bfloat16* q = qout + ((size_t)((b * 8 + h) * T + i)) * 128 + d;
#pragma unroll
      for (int e = 0; e < 8; ++e) {
        __hip_bfloat16 hi = __float2bfloat16(v[e]);
        q[e] = hi;
        q[64 + e] = __float2bfloat16(v[e] - __bfloat162float(hi));
      }
    } else {
      __hip_bfloat16* q = qout + ((size_t)((b * 8 + h) * T + i)) * 64 + d;
#pragma unroll
      for (int e = 0; e < 8; ++e) q[e] = __float2bfloat16(v[e]);
    }
  } else {
    int cc = c8 - 512, h = cc >> 6, d = cc & 63;
    if (Q_SPLIT) {
      __hip_bfloat16* k = kout + ((size_t)((b * 8 + h) * T + i)) * 64 + d;
#pragma unroll
      for (int e = 0; e < 8; ++e) k[e] = __float2bfloat16(v[e]);
    } else {
      __hip_bfloat16* k = kout + ((size_t)((b * 8 + h) * T + i)) * 128 + d;
#pragma unroll
      for (int e = 0; e < 8; ++e) {
        __hip_bfloat16 hi = __float2bfloat16(v[e]);
        k[e] = hi;
        k[64 + e] = __float2bfloat16(v[e] - __bfloat162float(hi));
      }
    }
  }
}

// ---------------- v transpose: qkv v-part -> bf16 [bh][d][token] ----------------
__global__ __launch_bounds__(256)
void vtrans_kernel(const float* __restrict__ qkv, __hip_bfloat16* __restrict__ vT, int T) {
  __shared__ float t[64][65];
  const int bh = blockIdx.x, b = bh >> 3, h = bh & 7;
  const int i0 = blockIdx.y * 64;
  const int tid = threadIdx.x;
#pragma unroll
  for (int it = 0; it < 4; ++it) {
    int idx = tid + it * 256, r = idx >> 4, f = idx & 15;
    float4 v = ldf4(qkv + (size_t)(b * T + i0 + r) * QLD + 2 * Dd + h * 64 + f * 4);
    t[r][f * 4 + 0] = v.x; t[r][f * 4 + 1] = v.y;
    t[r][f * 4 + 2] = v.z; t[r][f * 4 + 3] = v.w;
  }
  __syncthreads();
#pragma unroll
  for (int it = 0; it < 4; ++it) {
    int idx = tid + it * 256, d = idx >> 4, c4 = (idx & 15) * 4;
    __hip_bfloat16* op = vT + (size_t)(bh * 64 + d) * T + i0 + c4;
#pragma unroll
    for (int e = 0; e < 4; ++e) op[e] = __float2bfloat16(t[c4 + e][d]);
  }
}

// ---------------- x-path softmax (dual e1/e24) + rd + atten write ----------------
// grid (Nn/16, CHUNK); S layout [zloc][i][j], 16 bh per chunk.
__global__ __launch_bounds__(256)
void softmax_x_kernel(const float* __restrict__ S, const float* __restrict__ rd,
                      __hip_bfloat16* __restrict__ P1, float* __restrict__ atten, int z0) {
  __shared__ float rd_s[MK][17];
  __shared__ float e24_s[16][261];
  const int tid = threadIdx.x, l = tid & 63, w = tid >> 6;
  const int zloc = blockIdx.y, bh = z0 + zloc, b = bh >> 3;
  const int i0 = blockIdx.x * 16;
  // rd tile: 256 j x 16 i
#pragma unroll
  for (int it = 0; it < 4; ++it) {
    int idx = tid + it * 256, j = idx >> 2, f = idx & 3;
    float4 v = ldf4(rd + (size_t)(b * MK + j) * Nn + i0 + f * 4);
    rd_s[j][f * 4 + 0] = v.x; rd_s[j][f * 4 + 1] = v.y;
    rd_s[j][f * 4 + 2] = v.z; rd_s[j][f * 4 + 3] = v.w;
  }
  __syncthreads();
#pragma unroll
  for (int rr = 0; rr < 4; ++rr) {
    const int r = w * 4 + rr;
    const int i = i0 + r;
    const float* sp = S + ((size_t)zloc * Nn + i) * MK;
    float d0 = sp[l], d1 = sp[l + 64], d2 = sp[l + 128], d3 = sp[l + 192];
    float mx = fmaxf(fmaxf(d0, d1), fmaxf(d2, d3));
    mx = waveMax(mx);
    float e10 = __expf(d0 - mx), e11 = __expf(d1 - mx), e12 = __expf(d2 - mx), e13 = __expf(d3 - mx);
    float f0 = __expf(24.f * (d0 - mx)), f1 = __expf(24.f * (d1 - mx));
    float f2 = __expf(24.f * (d2 - mx)), f3 = __expf(24.f * (d3 - mx));
    float s1 = waveSum(e10 + e11 + e12 + e13);
    float s24 = waveSum(f0 + f1 + f2 + f3);
    const float i1 = 1.f / s1, i24 = 1.f / s24;
    __hip_bfloat16* pp = P1 + ((size_t)bh * Nn + i) * MK;
    float r0 = rd_s[l][r], r1 = rd_s[l + 64][r], r2 = rd_s[l + 128][r], r3 = rd_s[l + 192][r];
    pp[l]       = __float2bfloat16(e10 * i1 * r0);
    pp[l + 64]  = __float2bfloat16(e11 * i1 * r1);
    pp[l + 128] = __float2bfloat16(e12 * i1 * r2);
    pp[l + 192] = __float2bfloat16(e13 * i1 * r3);
    e24_s[r][l]       = f0 * i24 * r0;
    e24_s[r][l + 64]  = f1 * i24 * r1;
    e24_s[r][l + 128] = f2 * i24 * r2;
    e24_s[r][l + 192] = f3 * i24 * r3;
  }
  __syncthreads();
  // atten[bh][j][i0..i0+16) ; lanes: 4 j x 16 i per instruction
  const int iL = l & 15, jg = l >> 4;
#pragma unroll
  for (int jj = 0; jj < 16; ++jj) {
    int j = w * 64 + jj * 4 + jg;
    atten[((size_t)bh * MK + j) * Nn + i0 + iL] = e24_s[iL][j];
  }
}

// ---------------- k-path softmax + rd ----------------
// grid (MK, CHUNK); S layout [zloc][j][i]
__global__ __launch_bounds__(256)
void softmax_k_kernel(const float* __restrict__ S, const float* __restrict__ rd,
                      __hip_bfloat16* __restrict__ P2, int z0) {
  __shared__ float red8[8];
  const int tid = threadIdx.x;
  const int j = blockIdx.x, zloc = blockIdx.y, bh = z0 + zloc, b = bh >> 3;
  const float* row = S + ((size_t)zloc * MK + j) * Nn;
  float d[8];
  float lm = -3.4e38f;
#pragma unroll
  for (int c = 0; c < 8; ++c) { d[c] = row[c * 256 + tid]; lm = fmaxf(lm, d[c]); }
  const float mx = blockMax256(lm, red8);
  float ls = 0.f;
#pragma unroll
  for (int c = 0; c < 8; ++c) { d[c] = __expf(d[c] - mx); ls += d[c]; }
  const float s = blockSum256(ls, red8);
  const float inv = 1.f / s;
  const float* rp = rd + (size_t)(b * MK + j) * Nn;
  __hip_bfloat16* pp = P2 + ((size_t)bh * MK + j) * Nn;
#pragma unroll
  for (int c = 0; c < 8; ++c)
    pp[c * 256 + tid] = __float2bfloat16(d[c] * inv * rp[c * 256 + tid]);
}

// ------------- cls-token attention: grid B*H, block 256 -------------
__global__ __launch_bounds__(256)
void attn_c_kernel(const float* __restrict__ cqkv, const float* __restrict__ kqkv,
                   const float* __restrict__ mask, const float* __restrict__ kmask,
                   float* __restrict__ c_pre) {
  __shared__ __align__(16) float kv_s[MK][DH];
  __shared__ __align__(16) float q_s[DH];
  __shared__ float pbuf[MK];
  __shared__ float red8[8];
  __shared__ float redpv[4][DH];
  const int tid = threadIdx.x;
  const int bh = blockIdx.x, b = bh >> 3, h = bh & 7;
  const float* vp = kqkv + ((size_t)(b * MK + tid)) * QLD + 2 * Dd + h * DH;
#pragma unroll
  for (int q4 = 0; q4 < 16; ++q4)
    *reinterpret_cast<float4*>(&kv_s[tid][q4 * 4]) = ldf4(vp + q4 * 4);
  if (tid < DH) q_s[tid] = cqkv[(size_t)b * QLD + h * DH + tid];
  __syncthreads();
  const float* kp = kqkv + ((size_t)(b * MK + tid)) * QLD + Dd + h * DH;
  float dot = 0.f;
#pragma unroll
  for (int q4 = 0; q4 < 16; ++q4) {
    float4 kv4 = ldf4(kp + q4 * 4);
    float4 qv = ldf4(&q_s[q4 * 4]);
    dot = fmaf(qv.x, kv4.x, dot);
    dot = fmaf(qv.y, kv4.y, dot);
    dot = fmaf(qv.z, kv4.z, dot);
    dot = fmaf(qv.w, kv4.w, dot);
  }
  const float dm = (mask[(size_t)b * Nn] * kmask[b * MK + tid] < 0.5f) ? NEGV : dot * SCALE;
  const float mx = blockMax256(dm, red8);
  const float e = __expf(dm - mx);
  const float s = blockSum256(e, red8);
  pbuf[tid] = e / s;
  __syncthreads();
  const int d = tid & 63, g = tid >> 6;
  float acc = 0.f;
#pragma unroll 8
  for (int jj = 0; jj < 64; ++jj)
    acc = fmaf(pbuf[g * 64 + jj], kv_s[g * 64 + jj][d], acc);
  redpv[g][d] = acc;
  __syncthreads();
  if (tid < DH)
    c_pre[(size_t)b * Dd + h * DH + tid] =
        redpv[0][tid] + redpv[1][tid] + redpv[2][tid] + redpv[3][tid];
}

// ------------- output writers (float32 outputs) -------------
__global__ void kreps_kernel(const float* __restrict__ kx, const float* __restrict__ kmask,
                             float* __restrict__ o) {
  const int idx = blockIdx.x * 256 + threadIdx.x;
  const int bj = idx >> 9;
  const float keep = (kmask[bj] >= 0.5f) ? 1.f : 0.f;
  o[idx] = kx[idx] * keep;
}
__global__ void cout_kernel(const float* __restrict__ c_s, float* __restrict__ o) {
  const int idx = blockIdx.x * 256 + threadIdx.x;
  o[idx] = c_s[idx];
}

static GArgs ga_base() { GArgs g = {}; return g; }

extern "C" void kernel_launch(void* const* d_in, const int* in_sizes, int n_in,
                              void* d_out, int out_size, void* d_ws, size_t ws_size,
                              hipStream_t stream) {
  (void)in_sizes; (void)n_in; (void)out_size; (void)ws_size;
  const float* x_in  = (const float*)d_in[0];
  const float* kx_in = (const float*)d_in[1];
  const float* rd    = (const float*)d_in[2];
  const float* c_in  = (const float*)d_in[3];
  const float* mask  = (const float*)d_in[4];
  const float* kmask = (const float*)d_in[5];
  const float* ln1g  = (const float*)d_in[6];
  const float* ln1b  = (const float*)d_in[7];
  const float* Wqkv  = (const float*)d_in[8];
  const float* Woutw = (const float*)d_in[9];
  const float* boutw = (const float*)d_in[10];
  const float* ln2g  = (const float*)d_in[11];
  const float* ln2b  = (const float*)d_in[12];
  const float* W1    = (const float*)d_in[13];
  const float* b1    = (const float*)d_in[14];
  const float* W2    = (const float*)d_in[15];
  const float* b2    = (const float*)d_in[16];
  float* out = (float*)d_out;

  float* ws = (float*)d_ws;
  size_t off = 0;
  auto alloc = [&](size_t n) { float* p = ws + off; off += (n + 15) & ~(size_t)15; return p; };
  float* x_s   = alloc((size_t)Bb * Nn * Dd);
  float* xn    = alloc((size_t)Bb * Nn * Dd);
  float* xn_bf_f = alloc((size_t)Bb * Nn * Dd / 2);
  float* kx_s  = alloc((size_t)Bb * MK * Dd);
  float* kxn   = alloc((size_t)Bb * MK * Dd);
  float* kxn_bf_f = alloc((size_t)Bb * MK * Dd / 2);
  float* c_s   = alloc((size_t)Bb * Dd);
  float* cn    = alloc((size_t)Bb * Dd);
  float* cqkv  = alloc((size_t)Bb * QLD);
  float* chid  = alloc((size_t)Bb * MLPD);
  float* c_pre = alloc((size_t)Bb * Dd);
  float* tqkv  = alloc((size_t)Bb * Nn * QLD);       // hosts P / hid later
  float* kqkv  = alloc((size_t)Bb * MK * QLD);       // hosts hid_kx later
  float* S     = alloc((size_t)16 * Nn * MK);        // score scratch, 16 bh per chunk
  float* tq_s_f  = alloc((size_t)32 * Nn * 128 / 2);
  float* kk_s_f  = alloc((size_t)32 * MK * 128 / 2);
  float* tk_hi_f = alloc((size_t)32 * Nn * 64 / 2);
  float* kq_hi_f = alloc((size_t)32 * MK * 64 / 2);
  float* tvT_f   = alloc((size_t)32 * 64 * Nn / 2);
  float* kvT_f   = alloc((size_t)32 * 64 * MK / 2);
  float* xpre_f  = alloc((size_t)Bb * Nn * Dd / 2);
  float* kxpre_f = alloc((size_t)Bb * MK * Dd / 2);
  float* WqkvT_f = alloc((size_t)QLD * Dd / 2);
  float* WoutT_f = alloc((size_t)Dd * Dd / 2);
  float* W1T_f   = alloc((size_t)MLPD * Dd / 2);
  float* W2T_f   = alloc((size_t)Dd * MLPD / 2);

  __hip_bfloat16* xn_bf  = (__hip_bfloat16*)xn_bf_f;
  __hip_bfloat16* kxn_bf = (__hip_bfloat16*)kxn_bf_f;
  __hip_bfloat16* tq_s   = (__hip_bfloat16*)tq_s_f;
  __hip_bfloat16* kk_s   = (__hip_bfloat16*)kk_s_f;
  __hip_bfloat16* tk_hi  = (__hip_bfloat16*)tk_hi_f;
  __hip_bfloat16* kq_hi  = (__hip_bfloat16*)kq_hi_f;
  __hip_bfloat16* tvT    = (__hip_bfloat16*)tvT_f;
  __hip_bfloat16* kvT    = (__hip_bfloat16*)kvT_f;
  __hip_bfloat16* x_pre  = (__hip_bfloat16*)xpre_f;
  __hip_bfloat16* kx_pre = (__hip_bfloat16*)kxpre_f;
  __hip_bfloat16* WqkvT  = (__hip_bfloat16*)WqkvT_f;
  __hip_bfloat16* WoutT  = (__hip_bfloat16*)WoutT_f;
  __hip_bfloat16* W1T    = (__hip_bfloat16*)W1T_f;
  __hip_bfloat16* W2T    = (__hip_bfloat16*)W2T_f;
  __hip_bfloat16* Pbuf   = (__hip_bfloat16*)tqkv;    // P1 / P2 overlay
  __hip_bfloat16* hid    = (__hip_bfloat16*)tqkv;    // FF hidden overlay
  __hip_bfloat16* hid_kx = (__hip_bfloat16*)kqkv;

  const size_t CL_OFF = (size_t)2 * Bb * MK * Dd;
  const size_t AT_OFF = CL_OFF + (size_t)Bb * Dd;

  for (int l = 0; l < 2; ++l) {
    const float* xp  = (l == 0) ? x_in  : x_s;
    const float* kxp = (l == 0) ? kx_in : kx_s;
    const float* cp  = (l == 0) ? c_in  : c_s;
    ln_kernel<<<Bb * Nn, 64, 0, stream>>>(xp,  ln1g + l * Dd, ln1b + l * Dd, xn,  xn_bf);
    ln_kernel<<<Bb * MK, 64, 0, stream>>>(kxp, ln1g + l * Dd, ln1b + l * Dd, kxn, kxn_bf);
    ln_kernel<<<Bb,      64, 0, stream>>>(cp,  ln1g + l * Dd, ln1b + l * Dd, cn,  nullptr);

    const float* Wq = Wqkv + (size_t)l * Dd * QLD;
    const float* Wo = Woutw + (size_t)l * Dd * Dd;
    const float* bo = boutw + (size_t)l * Dd;
    const float* W1l = W1 + (size_t)l * Dd * MLPD;
    const float* b1l = b1 + (size_t)l * MLPD;
    const float* W2l = W2 + (size_t)l * MLPD * Dd;
    const float* b2l = b2 + (size_t)l * Dd;
    wtrans_kernel<<<dim3(QLD / 64, Dd / 64), 256, 0, stream>>>(Wq, WqkvT, Dd, QLD);
    wtrans_kernel<<<dim3(Dd / 64, Dd / 64), 256, 0, stream>>>(Wo, WoutT, Dd, Dd);
    wtrans_kernel<<<dim3(MLPD / 64, Dd / 64), 256, 0, stream>>>(W1l, W1T, Dd, MLPD);
    wtrans_kernel<<<dim3(Dd / 64, MLPD / 64), 256, 0, stream>>>(W2l, W2T, MLPD, Dd);

    // QKV
    {
      GArgs g = ga_base();
      g.A = (const short*)xn_bf; g.lda = Dd;
      g.Bt = (const short*)WqkvT; g.ldb = Dd;
      g.C = tqkv; g.ldc = QLD;
      g.M = Bb * Nn; g.N = QLD; g.K = Dd;
      mgemm<128, 128, 0><<<dim3(QLD / 128, Bb * Nn / 128, 1), 256, 0, stream>>>(g);
      g.A = (const short*)kxn_bf; g.C = kqkv; g.M = Bb * MK;
      mgemm<128, 128, 0><<<dim3(QLD / 128, Bb * MK / 128, 1), 256, 0, stream>>>(g);
    }
    gemv4_kernel<false, false, false><<<QLD / 256, 256, 0, stream>>>(
        cn, Wq, nullptr, nullptr, cqkv, Dd, QLD);

    split_kernel<true><<<(Bb * Nn * 128) / 256, 256, 0, stream>>>(tqkv, tq_s, tk_hi, Nn);
    split_kernel<false><<<(Bb * MK * 128) / 256, 256, 0, stream>>>(kqkv, kq_hi, kk_s, MK);
    vtrans_kernel<<<dim3(32, Nn / 64), 256, 0, stream>>>(tqkv, tvT, Nn);
    vtrans_kernel<<<dim3(32, MK / 64), 256, 0, stream>>>(kqkv, kvT, MK);

    // ---- x-path attention ----
    for (int ch = 0; ch < 2; ++ch) {
      GArgs g = ga_base();
      g.A = (const short*)(tq_s + (size_t)ch * 16 * Nn * 128); g.asb = (long)Nn * 128; g.lda = 128;
      g.Bt = (const short*)(kk_s + (size_t)ch * 16 * MK * 128); g.bsb = (long)MK * 128; g.ldb = 128;
      g.C = S; g.czi = (long)Nn * MK; g.czo = 8L * Nn * MK; g.ldc = MK;
      g.rowm = mask; g.rms = Nn; g.colm = kmask; g.cms = MK;
      g.z0 = ch * 16; g.M = Nn; g.N = MK; g.K = 128;
      mgemm<128, 128, 1><<<dim3(MK / 128, Nn / 128, 16), 256, 0, stream>>>(g);
      softmax_x_kernel<<<dim3(Nn / 16, 16), 256, 0, stream>>>(
          S, rd, Pbuf, out + AT_OFF + (size_t)l * 32 * MK * Nn, ch * 16);
    }
    {
      GArgs g = ga_base();
      g.A = (const short*)Pbuf; g.asb = (long)Nn * MK; g.lda = MK;
      g.Bt = (const short*)kvT; g.bsb = (long)64 * MK; g.ldb = MK;
      g.Cb = x_pre; g.czo = (long)Nn * Dd; g.czi = 64; g.ldc = Dd;
      g.M = Nn; g.N = 64; g.K = MK;
      mgemm<128, 64, 4><<<dim3(1, Nn / 128, 32), 256, 0, stream>>>(g);
    }
    // ---- k-path attention ----
    for (int ch = 0; ch < 2; ++ch) {
      GArgs g = ga_base();
      g.A = (const short*)(kq_hi + (size_t)ch * 16 * MK * 64); g.asb = (long)MK * 64; g.lda = 64;
      g.Bt = (const short*)(tk_hi + (size_t)ch * 16 * Nn * 64); g.bsb = (long)Nn * 64; g.ldb = 64;
      g.C = S; g.czi = (long)MK * Nn; g.czo = 8L * MK * Nn; g.ldc = Nn;
      g.rowm = kmask; g.rms = MK; g.colm = mask; g.cms = Nn;
      g.z0 = ch * 16; g.M = MK; g.N = Nn; g.K = 64;
      mgemm<128, 128, 1><<<dim3(Nn / 128, MK / 128, 16), 256, 0, stream>>>(g);
      softmax_k_kernel<<<dim3(MK, 16), 256, 0, stream>>>(S, rd, Pbuf, ch * 16);
    }
    {
      GArgs g = ga_base();
      g.A = (const short*)Pbuf; g.asb = (long)MK * Nn; g.lda = Nn;
      g.Bt = (const short*)tvT; g.bsb = (long)64 * Nn; g.ldb = Nn;
      g.Cb = kx_pre; g.czo = (long)MK * Dd; g.czi = 64; g.ldc = Dd;
      g.M = MK; g.N = 64; g.K = Nn;
      mgemm<128, 64, 4><<<dim3(1, MK / 128, 32), 256, 0, stream>>>(g);
    }
    attn_c_kernel<<<Bb * Hh, 256, 0, stream>>>(cqkv, kqkv, mask, kmask, c_pre);

    // ---- Wout + residual ----
    {
      GArgs g = ga_base();
      g.A = (const short*)x_pre; g.lda = Dd;
      g.Bt = (const short*)WoutT; g.ldb = Dd;
      g.C = x_s; g.ldc = Dd; g.bias = bo; g.res = xn; g.ldr = Dd;
      g.M = Bb * Nn; g.N = Dd; g.K = Dd;
      mgemm<128, 128, 2><<<dim3(Dd / 128, Bb * Nn / 128, 1), 256, 0, stream>>>(g);
      g.A = (const short*)kx_pre; g.C = kx_s; g.res = kxn; g.M = Bb * MK;
      mgemm<128, 128, 2><<<dim3(Dd / 128, Bb * MK / 128, 1), 256, 0, stream>>>(g);
    }
    gemv4_kernel<true, false, true><<<Dd / 256, 256, 0, stream>>>(
        c_pre, Wo, bo, cn, c_s, Dd, Dd);

    // ---- FF x ----
    ln_kernel<<<Bb * Nn, 64, 0, stream>>>(x_s, ln2g + l * Dd, ln2b + l * Dd, xn, xn_bf);
    {
      GArgs g = ga_base();
      g.A = (const short*)xn_bf; g.lda = Dd;
      g.Bt = (const short*)W1T; g.ldb = Dd;
      g.Cb = hid; g.ldc = MLPD; g.bias = b1l;
      g.M = Bb * Nn; g.N = MLPD; g.K = Dd;
      mgemm<128, 128, 3><<<dim3(MLPD / 128, Bb * Nn / 128, 1), 256, 0, stream>>>(g);
      GArgs h = ga_base();
      h.A = (const short*)hid; h.lda = MLPD;
      h.Bt = (const short*)W2T; h.ldb = MLPD;
      h.C = x_s; h.ldc = Dd; h.bias = b2l; h.res = x_s; h.ldr = Dd;
      h.M = Bb * Nn; h.N = Dd; h.K = MLPD;
      mgemm<128, 128, 2><<<dim3(Dd / 128, Bb * Nn / 128, 1), 256, 0, stream>>>(h);
    }
    // ---- FF kx ----
    ln_kernel<<<Bb * MK, 64, 0, stream>>>(kx_s, ln2g + l * Dd, ln2b + l * Dd, kxn, kxn_bf);
    {
      GArgs g = ga_base();
      g.A = (const short*)kxn_bf; g.lda = Dd;
      g.Bt = (const short*)W1T; g.ldb = Dd;
      g.Cb = hid_kx; g.ldc = MLPD; g.bias = b1l;
      g.M = Bb * MK; g.N = MLPD; g.K = Dd;
      mgemm<128, 128, 3><<<dim3(MLPD / 128, Bb * MK / 128, 1), 256, 0, stream>>>(g);
      GArgs h = ga_base();
      h.A = (const short*)hid_kx; h.lda = MLPD;
      h.Bt = (const short*)W2T; h.ldb = MLPD;
      h.C = kx_s; h.ldc = Dd; h.bias = b2l; h.res = kx_s; h.ldr = Dd;
      h.M = Bb * MK; h.N = Dd; h.K = MLPD;
      mgemm<128, 128, 2><<<dim3(Dd / 128, Bb * MK / 128, 1), 256, 0, stream>>>(h);
    }
    // ---- FF c (gemv path) ----
    ln_kernel<<<Bb, 64, 0, stream>>>(c_s, ln2g + l * Dd, ln2b + l * Dd, cn, nullptr);
    gemv4_kernel<true, true,  false><<<MLPD / 256, 256, 0, stream>>>(
        cn, W1l, b1l, nullptr, chid, Dd, MLPD);
    gemv4_kernel<true, false, true><<<Dd / 256, 256, 0, stream>>>(
        chid, W2l, b2l, c_s, c_s, MLPD, Dd);

    kreps_kernel<<<(Bb * MK * Dd) / 256, 256, 0, stream>>>(kx_s, kmask,
                                                           out + (size_t)l * Bb * MK * Dd);
  }
  cout_kernel<<<(Bb * Dd) / 256, 256, 0, stream>>>(c_s, out + CL_OFF);
}

// Round 5
// 1247.682 us; speedup vs baseline: 3.5965x; 1.3949x over previous
//
#include <hip/hip_runtime.h>
#include <hip/hip_bf16.h>
#include <cstddef>

#define DEV __device__ __forceinline__

constexpr int Bb  = 4;
constexpr int Nn  = 2048;
constexpr int MK  = 256;
constexpr int Dd  = 512;
constexpr int Hh  = 8;
constexpr int DH  = 64;
constexpr int QLD = 1536;   // qkv row stride (3*512)
constexpr int MLPD = 2048;
constexpr int MKC = Bb * MK + Bb;   // kx rows + cls rows, concatenated (1028)
constexpr float SCALE = 0.125f;   // 64^-0.5
constexpr float NEGV  = -1e9f;

typedef __attribute__((ext_vector_type(8))) short short8;
typedef __attribute__((ext_vector_type(4))) float f32x4;

DEV float4 ldf4(const float* p) { return *reinterpret_cast<const float4*>(p); }

DEV float waveMax(float v) {
#pragma unroll
  for (int o = 32; o; o >>= 1) v = fmaxf(v, __shfl_xor(v, o));
  return v;
}
DEV float waveSum(float v) {
#pragma unroll
  for (int o = 32; o; o >>= 1) v += __shfl_xor(v, o);
  return v;
}
DEV float blockMax256(float v, float* red) {
  v = waveMax(v);
  __syncthreads();
  if ((threadIdx.x & 63) == 0) red[threadIdx.x >> 6] = v;
  __syncthreads();
  return fmaxf(fmaxf(red[0], red[1]), fmaxf(red[2], red[3]));
}
DEV float blockSum256(float v, float* red) {
  v = waveSum(v);
  __syncthreads();
  if ((threadIdx.x & 63) == 0) red[threadIdx.x >> 6] = v;
  __syncthreads();
  return red[0] + red[1] + red[2] + red[3];
}
DEV float gelu_f(float x) { return 0.5f * x * (1.f + erff(x * 0.70710678118654752f)); }

// ---------------- LayerNorm: one wave per 512-float row, dual f32+bf16 out ----------------
__global__ __launch_bounds__(64)
void ln_kernel(const float* __restrict__ in, const float* __restrict__ gw,
               const float* __restrict__ bw, float* __restrict__ out,
               __hip_bfloat16* __restrict__ outb) {
  const int row = blockIdx.x;
  const int t = threadIdx.x;
  const float* p = in + (size_t)row * Dd + t * 8;
  float4 v0 = ldf4(p), v1 = ldf4(p + 4);
  float s = v0.x + v0.y + v0.z + v0.w + v1.x + v1.y + v1.z + v1.w;
  float q = v0.x*v0.x + v0.y*v0.y + v0.z*v0.z + v0.w*v0.w
          + v1.x*v1.x + v1.y*v1.y + v1.z*v1.z + v1.w*v1.w;
  s = waveSum(s); q = waveSum(q);
  const float mu = s * (1.f / Dd);
  const float rstd = rsqrtf(fmaxf(q * (1.f / Dd) - mu * mu, 0.f) + 1e-5f);
  float4 g0 = ldf4(gw + t * 8), g1 = ldf4(gw + t * 8 + 4);
  float4 b0 = ldf4(bw + t * 8), b1 = ldf4(bw + t * 8 + 4);
  float o[8];
  o[0] = (v0.x - mu) * rstd * g0.x + b0.x;
  o[1] = (v0.y - mu) * rstd * g0.y + b0.y;
  o[2] = (v0.z - mu) * rstd * g0.z + b0.z;
  o[3] = (v0.w - mu) * rstd * g0.w + b0.w;
  o[4] = (v1.x - mu) * rstd * g1.x + b1.x;
  o[5] = (v1.y - mu) * rstd * g1.y + b1.y;
  o[6] = (v1.z - mu) * rstd * g1.z + b1.z;
  o[7] = (v1.w - mu) * rstd * g1.w + b1.w;
  float* op = out + (size_t)row * Dd + t * 8;
  *reinterpret_cast<float4*>(op)     = make_float4(o[0], o[1], o[2], o[3]);
  *reinterpret_cast<float4*>(op + 4) = make_float4(o[4], o[5], o[6], o[7]);
  if (outb) {
    __hip_bfloat16* ob = outb + (size_t)row * Dd + t * 8;
#pragma unroll
    for (int e = 0; e < 8; ++e) ob[e] = __float2bfloat16(o[e]);
  }
}

// ---------------- bf16 MFMA GEMM ----------------
// C[M,N] = A[M,K] @ Bt[N,K]^T, batched over blockIdx.z. 256 threads.
// EPI: 0 = f32 write; 1 = mask+scale f32 (scores); 2 = +bias +res f32;
//      3 = +bias, gelu, bf16 write; 4 = bf16 write.
struct GArgs {
  const short* A;  long asb; int lda;
  const short* Bt; long bsb; int ldb;
  float* C; __hip_bfloat16* Cb;
  long czo, czi; int ldc;
  const float* bias;
  const float* res; int ldr;
  const float* rowm; int rms;
  const float* colm; int cms;
  int z0, M, N, K;
};

template<int BM, int BN, int EPI>
__global__ __launch_bounds__(256)
void mgemm(GArgs g) {
  constexpr int WMW = (BN >= 128) ? 2 : 4;
  constexpr int WNW = 4 / WMW;
  constexpr int WM = BM / WMW, WN = BN / WNW;
  constexpr int FM = WM / 16, FN = WN / 16;
  __shared__ short As[BM * 64];
  __shared__ short Bs[BN * 64];
  const int tid = threadIdx.x, l = tid & 63, w = tid >> 6;
  const int wm = (WNW == 2) ? (w >> 1) : w;
  const int wn = (WNW == 2) ? (w & 1) : 0;
  const int bx = blockIdx.x, by = blockIdx.y, z = blockIdx.z;
  const short* Ab = g.A + (size_t)z * g.asb;
  const short* Bb_ = g.Bt + (size_t)z * g.bsb;
  f32x4 acc[FM][FN] = {};
  const int lr = l & 15, lg = l >> 4;

  for (int k0 = 0; k0 < g.K; k0 += 64) {
    __syncthreads();
#pragma unroll
    for (int it = 0; it < BM / 32; ++it) {
      int idx = tid + it * 256, r = idx >> 3, c8 = (idx & 7) * 8;
      int gm = by * BM + r;
      short8 v = {};
      if (gm < g.M) v = *reinterpret_cast<const short8*>(Ab + (size_t)gm * g.lda + k0 + c8);
      int off = (r * 128 + c8 * 2) ^ ((r & 7) << 4);
      *reinterpret_cast<short8*>(reinterpret_cast<char*>(As) + off) = v;
    }
#pragma unroll
    for (int it = 0; it < BN / 32; ++it) {
      int idx = tid + it * 256, r = idx >> 3, c8 = (idx & 7) * 8;
      int gn = bx * BN + r;
      short8 v = *reinterpret_cast<const short8*>(Bb_ + (size_t)gn * g.ldb + k0 + c8);
      int off = (r * 128 + c8 * 2) ^ ((r & 7) << 4);
      *reinterpret_cast<short8*>(reinterpret_cast<char*>(Bs) + off) = v;
    }
    __syncthreads();
#pragma unroll
    for (int ks = 0; ks < 2; ++ks) {
      const int kb = (ks * 32 + lg * 8) * 2;
      short8 a[FM], b[FN];
#pragma unroll
      for (int fm = 0; fm < FM; ++fm) {
        int r = wm * WM + fm * 16 + lr;
        a[fm] = *reinterpret_cast<const short8*>(
            reinterpret_cast<const char*>(As) + ((r * 128 + kb) ^ ((r & 7) << 4)));
      }
#pragma unroll
      for (int fn = 0; fn < FN; ++fn) {
        int r = wn * WN + fn * 16 + lr;
        b[fn] = *reinterpret_cast<const short8*>(
            reinterpret_cast<const char*>(Bs) + ((r * 128 + kb) ^ ((r & 7) << 4)));
      }
#pragma unroll
      for (int fm = 0; fm < FM; ++fm)
#pragma unroll
        for (int fn = 0; fn < FN; ++fn)
          acc[fm][fn] = __builtin_amdgcn_mfma_f32_16x16x32_bf16(a[fm], b[fn], acc[fm][fn], 0, 0, 0);
    }
  }

  const int bg = (g.z0 + z) >> 3;
  const size_t zoff = (size_t)(z >> 3) * g.czo + (size_t)(z & 7) * g.czi;
#pragma unroll
  for (int fm = 0; fm < FM; ++fm) {
#pragma unroll
    for (int fn = 0; fn < FN; ++fn) {
#pragma unroll
      for (int r = 0; r < 4; ++r) {
        int m = by * BM + wm * WM + fm * 16 + lg * 4 + r;
        int n = bx * BN + wn * WN + fn * 16 + lr;
        if (m >= g.M) continue;
        float v = acc[fm][fn][r];
        size_t coff = zoff + (size_t)m * g.ldc + n;
        if (EPI == 0) {
          g.C[coff] = v;
        } else if (EPI == 1) {
          float rm = g.rowm[(size_t)bg * g.rms + m];
          float cm = g.colm[(size_t)bg * g.cms + n];
          g.C[coff] = (rm * cm < 0.5f) ? NEGV : v * SCALE;
        } else if (EPI == 2) {
          v += g.bias[n] + g.res[(size_t)m * g.ldr + n];
          g.C[coff] = v;
        } else if (EPI == 3) {
          v = gelu_f(v + g.bias[n]);
          g.Cb[coff] = __float2bfloat16(v);
        } else {
          g.Cb[coff] = __float2bfloat16(v);
        }
      }
    }
  }
}

// ---------------- weight transpose: f32 [K][N] -> bf16 [N][K] ----------------
__global__ __launch_bounds__(256)
void wtrans_kernel(const float* __restrict__ W, __hip_bfloat16* __restrict__ WT,
                   int K, int N) {
  __shared__ float t[64][65];
  const int n0 = blockIdx.x * 64, k0 = blockIdx.y * 64;
  const int tid = threadIdx.x;
#pragma unroll
  for (int it = 0; it < 4; ++it) {
    int idx = tid + it * 256, r = idx >> 4, f = idx & 15;
    float4 v = ldf4(W + (size_t)(k0 + r) * N + n0 + f * 4);
    t[r][f * 4 + 0] = v.x; t[r][f * 4 + 1] = v.y;
    t[r][f * 4 + 2] = v.z; t[r][f * 4 + 3] = v.w;
  }
  __syncthreads();
#pragma unroll
  for (int it = 0; it < 4; ++it) {
    int idx = tid + it * 256, r = idx >> 4, c4 = (idx & 15) * 4;
    __hip_bfloat16* op = WT + (size_t)(n0 + r) * K + k0 + c4;
#pragma unroll
    for (int e = 0; e < 4; ++e) op[e] = __float2bfloat16(t[c4 + e][r]);
  }
}

// ---------------- qkv split: hi/lo bf16 operand prep ----------------
template<bool Q_SPLIT>
__global__ __launch_bounds__(256)
void split_kernel(const float* __restrict__ qkv, __hip_bfloat16* __restrict__ qout,
                  __hip_bfloat16* __restrict__ kout, int T) {
  const int idx = blockIdx.x * 256 + threadIdx.x;     // B*T*128 items
  const int token = idx >> 7, c8 = (idx & 127) * 8;
  const int b = token / T, i = token - b * T;
  const float* p = qkv + (size_t)token * QLD + c8;
  float v[8];
  float4 a = ldf4(p), c = ldf4(p + 4);
  v[0]=a.x; v[1]=a.y; v[2]=a.z; v[3]=a.w; v[4]=c.x; v[5]=c.y; v[6]=c.z; v[7]=c.w;
  if (c8 < 512) {
    int h = c8 >> 6, d = c8 & 63;
    if (Q_SPLIT) {
      __hip_bfloat16* q = qout + ((size_t)((b * 8 + h) * T + i)) * 128 + d;
#pragma unroll
      for (int e = 0; e < 8; ++e) {
        __hip_bfloat16 hi = __float2bfloat16(v[e]);
        q[e] = hi;
        q[64 + e] = __float2bfloat16(v[e] - __bfloat162float(hi));
      }
    } else {
      __hip_bfloat16* q = qout + ((size_t)((b * 8 + h) * T + i)) * 64 + d;
#pragma unroll
      for (int e = 0; e < 8; ++e) q[e] = __float2bfloat16(v[e]);
    }
  } else {
    int cc = c8 - 512, h = cc >> 6, d = cc & 63;
    if (Q_SPLIT) {
      __hip_bfloat16* k = kout + ((size_t)((b * 8 + h) * T + i)) * 64 + d;
#pragma unroll
      for (int e = 0; e < 8; ++e) k[e] = __float2bfloat16(v[e]);
    } else {
      __hip_bfloat16* k = kout + ((size_t)((b * 8 + h) * T + i)) * 128 + d;
#pragma unroll
      for (int e = 0; e < 8; ++e) {
        __hip_bfloat16 hi = __float2bfloat16(v[e]);
        k[e] = hi;
        k[64 + e] = __float2bfloat16(v[e] - __bfloat162float(hi));
      }
    }
  }
}

// ---------------- v transpose: qkv v-part -> bf16 [bh][d][token] ----------------
__global__ __launch_bounds__(256)
void vtrans_kernel(const float* __restrict__ qkv, __hip_bfloat16* __restrict__ vT, int T) {
  __shared__ float t[64][65];
  const int bh = blockIdx.x, b = bh >> 3, h = bh & 7;
  const int i0 = blockIdx.y * 64;
  const int tid = threadIdx.x;
#pragma unroll
  for (int it = 0; it < 4; ++it) {
    int idx = tid + it * 256, r = idx >> 4, f = idx & 15;
    float4 v = ldf4(qkv + (size_t)(b * T + i0 + r) * QLD + 2 * Dd + h * 64 + f * 4);
    t[r][f * 4 + 0] = v.x; t[r][f * 4 + 1] = v.y;
    t[r][f * 4 + 2] = v.z; t[r][f * 4 + 3] = v.w;
  }
  __syncthreads();
#pragma unroll
  for (int it = 0; it < 4; ++it) {
    int idx = tid + it * 256, d = idx >> 4, c4 = (idx & 15) * 4;
    __hip_bfloat16* op = vT + (size_t)(bh * 64 + d) * T + i0 + c4;
#pragma unroll
    for (int e = 0; e < 4; ++e) op[e] = __float2bfloat16(t[c4 + e][d]);
  }
}

// ---------------- x-path softmax (dual e1/e24) + rd + atten write ----------------
__global__ __launch_bounds__(256)
void softmax_x_kernel(const float* __restrict__ S, const float* __restrict__ rd,
                      __hip_bfloat16* __restrict__ P1, float* __restrict__ atten, int z0) {
  __shared__ float rd_s[MK][17];
  __shared__ float e24_s[16][261];
  const int tid = threadIdx.x, l = tid & 63, w = tid >> 6;
  const int zloc = blockIdx.y, bh = z0 + zloc, b = bh >> 3;
  const int i0 = blockIdx.x * 16;
#pragma unroll
  for (int it = 0; it < 4; ++it) {
    int idx = tid + it * 256, j = idx >> 2, f = idx & 3;
    float4 v = ldf4(rd + (size_t)(b * MK + j) * Nn + i0 + f * 4);
    rd_s[j][f * 4 + 0] = v.x; rd_s[j][f * 4 + 1] = v.y;
    rd_s[j][f * 4 + 2] = v.z; rd_s[j][f * 4 + 3] = v.w;
  }
  __syncthreads();
#pragma unroll
  for (int rr = 0; rr < 4; ++rr) {
    const int r = w * 4 + rr;
    const int i = i0 + r;
    const float* sp = S + ((size_t)zloc * Nn + i) * MK;
    float d0 = sp[l], d1 = sp[l + 64], d2 = sp[l + 128], d3 = sp[l + 192];
    float mx = fmaxf(fmaxf(d0, d1), fmaxf(d2, d3));
    mx = waveMax(mx);
    float e10 = __expf(d0 - mx), e11 = __expf(d1 - mx), e12 = __expf(d2 - mx), e13 = __expf(d3 - mx);
    float f0 = __expf(24.f * (d0 - mx)), f1 = __expf(24.f * (d1 - mx));
    float f2 = __expf(24.f * (d2 - mx)), f3 = __expf(24.f * (d3 - mx));
    float s1 = waveSum(e10 + e11 + e12 + e13);
    float s24 = waveSum(f0 + f1 + f2 + f3);
    const float i1 = 1.f / s1, i24 = 1.f / s24;
    __hip_bfloat16* pp = P1 + ((size_t)bh * Nn + i) * MK;
    float r0 = rd_s[l][r], r1 = rd_s[l + 64][r], r2 = rd_s[l + 128][r], r3 = rd_s[l + 192][r];
    pp[l]       = __float2bfloat16(e10 * i1 * r0);
    pp[l + 64]  = __float2bfloat16(e11 * i1 * r1);
    pp[l + 128] = __float2bfloat16(e12 * i1 * r2);
    pp[l + 192] = __float2bfloat16(e13 * i1 * r3);
    e24_s[r][l]       = f0 * i24 * r0;
    e24_s[r][l + 64]  = f1 * i24 * r1;
    e24_s[r][l + 128] = f2 * i24 * r2;
    e24_s[r][l + 192] = f3 * i24 * r3;
  }
  __syncthreads();
  const int iL = l & 15, jg = l >> 4;
#pragma unroll
  for (int jj = 0; jj < 16; ++jj) {
    int j = w * 64 + jj * 4 + jg;
    atten[((size_t)bh * MK + j) * Nn + i0 + iL] = e24_s[iL][j];
  }
}

// ---------------- k-path softmax + rd ----------------
__global__ __launch_bounds__(256)
void softmax_k_kernel(const float* __restrict__ S, const float* __restrict__ rd,
                      __hip_bfloat16* __restrict__ P2, int z0) {
  __shared__ float red8[8];
  const int tid = threadIdx.x;
  const int j = blockIdx.x, zloc = blockIdx.y, bh = z0 + zloc, b = bh >> 3;
  const float* row = S + ((size_t)zloc * MK + j) * Nn;
  float d[8];
  float lm = -3.4e38f;
#pragma unroll
  for (int c = 0; c < 8; ++c) { d[c] = row[c * 256 + tid]; lm = fmaxf(lm, d[c]); }
  const float mx = blockMax256(lm, red8);
  float ls = 0.f;
#pragma unroll
  for (int c = 0; c < 8; ++c) { d[c] = __expf(d[c] - mx); ls += d[c]; }
  const float s = blockSum256(ls, red8);
  const float inv = 1.f / s;
  const float* rp = rd + (size_t)(b * MK + j) * Nn;
  __hip_bfloat16* pp = P2 + ((size_t)bh * MK + j) * Nn;
#pragma unroll
  for (int c = 0; c < 8; ++c)
    pp[c * 256 + tid] = __float2bfloat16(d[c] * inv * rp[c * 256 + tid]);
}

// ------------- cls-token attention: grid B*H, block 256, bf16 out -------------
__global__ __launch_bounds__(256)
void attn_c_kernel(const float* __restrict__ cqkv, const float* __restrict__ kqkv,
                   const float* __restrict__ mask, const float* __restrict__ kmask,
                   __hip_bfloat16* __restrict__ c_pre) {
  __shared__ __align__(16) float kv_s[MK][DH];
  __shared__ __align__(16) float q_s[DH];
  __shared__ float pbuf[MK];
  __shared__ float red8[8];
  __shared__ float redpv[4][DH];
  const int tid = threadIdx.x;
  const int bh = blockIdx.x, b = bh >> 3, h = bh & 7;
  const float* vp = kqkv + ((size_t)(b * MK + tid)) * QLD + 2 * Dd + h * DH;
#pragma unroll
  for (int q4 = 0; q4 < 16; ++q4)
    *reinterpret_cast<float4*>(&kv_s[tid][q4 * 4]) = ldf4(vp + q4 * 4);
  if (tid < DH) q_s[tid] = cqkv[(size_t)b * QLD + h * DH + tid];
  __syncthreads();
  const float* kp = kqkv + ((size_t)(b * MK + tid)) * QLD + Dd + h * DH;
  float dot = 0.f;
#pragma unroll
  for (int q4 = 0; q4 < 16; ++q4) {
    float4 kv4 = ldf4(kp + q4 * 4);
    float4 qv = ldf4(&q_s[q4 * 4]);
    dot = fmaf(qv.x, kv4.x, dot);
    dot = fmaf(qv.y, kv4.y, dot);
    dot = fmaf(qv.z, kv4.z, dot);
    dot = fmaf(qv.w, kv4.w, dot);
  }
  const float dm = (mask[(size_t)b * Nn] * kmask[b * MK + tid] < 0.5f) ? NEGV : dot * SCALE;
  const float mx = blockMax256(dm, red8);
  const float e = __expf(dm - mx);
  const float s = blockSum256(e, red8);
  pbuf[tid] = e / s;
  __syncthreads();
  const int d = tid & 63, g = tid >> 6;
  float acc = 0.f;
#pragma unroll 8
  for (int jj = 0; jj < 64; ++jj)
    acc = fmaf(pbuf[g * 64 + jj], kv_s[g * 64 + jj][d], acc);
  redpv[g][d] = acc;
  __syncthreads();
  if (tid < DH)
    c_pre[(size_t)b * Dd + h * DH + tid] = __float2bfloat16(
        redpv[0][tid] + redpv[1][tid] + redpv[2][tid] + redpv[3][tid]);
}

// ------------- output writers (float32 outputs) -------------
__global__ void kreps_kernel(const float* __restrict__ kx, const float* __restrict__ kmask,
                             float* __restrict__ o) {
  const int idx = blockIdx.x * 256 + threadIdx.x;
  const int bj = idx >> 9;
  const float keep = (kmask[bj] >= 0.5f) ? 1.f : 0.f;
  o[idx] = kx[idx] * keep;
}
__global__ void cout_kernel(const float* __restrict__ c_s, float* __restrict__ o) {
  const int idx = blockIdx.x * 256 + threadIdx.x;
  o[idx] = c_s[idx];
}

static GArgs ga_base() { GArgs g = {}; return g; }

extern "C" void kernel_launch(void* const* d_in, const int* in_sizes, int n_in,
                              void* d_out, int out_size, void* d_ws, size_t ws_size,
                              hipStream_t stream) {
  (void)in_sizes; (void)n_in; (void)out_size; (void)ws_size;
  const float* x_in  = (const float*)d_in[0];
  const float* kx_in = (const float*)d_in[1];
  const float* rd    = (const float*)d_in[2];
  const float* c_in  = (const float*)d_in[3];
  const float* mask  = (const float*)d_in[4];
  const float* kmask = (const float*)d_in[5];
  const float* ln1g  = (const float*)d_in[6];
  const float* ln1b  = (const float*)d_in[7];
  const float* Wqkv  = (const float*)d_in[8];
  const float* Woutw = (const float*)d_in[9];
  const float* boutw = (const float*)d_in[10];
  const float* ln2g  = (const float*)d_in[11];
  const float* ln2b  = (const float*)d_in[12];
  const float* W1    = (const float*)d_in[13];
  const float* b1    = (const float*)d_in[14];
  const float* W2    = (const float*)d_in[15];
  const float* b2    = (const float*)d_in[16];
  float* out = (float*)d_out;

  float* ws = (float*)d_ws;
  size_t off = 0;
  auto alloc = [&](size_t n) { float* p = ws + off; off += (n + 15) & ~(size_t)15; return p; };
  float* x_s    = alloc((size_t)Bb * Nn * Dd);
  float* xn     = alloc((size_t)Bb * Nn * Dd);
  float* xn_bf_f = alloc((size_t)Bb * Nn * Dd / 2);
  // kx/cls concatenated buffers: cls rows appended after Bb*MK rows
  float* kc_s   = alloc((size_t)MKC * Dd);
  float* kcxn   = alloc((size_t)MKC * Dd);
  float* kcxn_bf_f = alloc((size_t)MKC * Dd / 2);
  float* kcqkv  = alloc((size_t)MKC * QLD);          // hosts hid_kc later
  float* kcpre_f = alloc((size_t)MKC * Dd / 2);
  float* tqkv   = alloc((size_t)Bb * Nn * QLD);      // hosts P / hid-x later
  float* S      = alloc((size_t)16 * Nn * MK);       // score scratch, 16 bh per chunk
  float* tq_s_f  = alloc((size_t)32 * Nn * 128 / 2);
  float* kk_s_f  = alloc((size_t)32 * MK * 128 / 2);
  float* tk_hi_f = alloc((size_t)32 * Nn * 64 / 2);
  float* kq_hi_f = alloc((size_t)32 * MK * 64 / 2);
  float* tvT_f   = alloc((size_t)32 * 64 * Nn / 2);
  float* kvT_f   = alloc((size_t)32 * 64 * MK / 2);
  float* xpre_f  = alloc((size_t)Bb * Nn * Dd / 2);
  float* WqkvT_f = alloc((size_t)QLD * Dd / 2);
  float* WoutT_f = alloc((size_t)Dd * Dd / 2);
  float* W1T_f   = alloc((size_t)MLPD * Dd / 2);
  float* W2T_f   = alloc((size_t)Dd * MLPD / 2);

  float* kx_s = kc_s;                    // rows [0, Bb*MK)
  float* c_s  = kc_s + (size_t)Bb * MK * Dd;
  float* kxn  = kcxn;
  float* cn   = kcxn + (size_t)Bb * MK * Dd;
  float* kqkv = kcqkv;
  float* cqkv = kcqkv + (size_t)Bb * MK * QLD;

  __hip_bfloat16* xn_bf  = (__hip_bfloat16*)xn_bf_f;
  __hip_bfloat16* kcxn_bf = (__hip_bfloat16*)kcxn_bf_f;
  __hip_bfloat16* kxn_bf = kcxn_bf;
  __hip_bfloat16* cn_bf  = kcxn_bf + (size_t)Bb * MK * Dd;
  __hip_bfloat16* kc_pre = (__hip_bfloat16*)kcpre_f;
  __hip_bfloat16* kx_pre = kc_pre;
  __hip_bfloat16* c_pre  = kc_pre + (size_t)Bb * MK * Dd;
  __hip_bfloat16* tq_s   = (__hip_bfloat16*)tq_s_f;
  __hip_bfloat16* kk_s   = (__hip_bfloat16*)kk_s_f;
  __hip_bfloat16* tk_hi  = (__hip_bfloat16*)tk_hi_f;
  __hip_bfloat16* kq_hi  = (__hip_bfloat16*)kq_hi_f;
  __hip_bfloat16* tvT    = (__hip_bfloat16*)tvT_f;
  __hip_bfloat16* kvT    = (__hip_bfloat16*)kvT_f;
  __hip_bfloat16* x_pre  = (__hip_bfloat16*)xpre_f;
  __hip_bfloat16* WqkvT  = (__hip_bfloat16*)WqkvT_f;
  __hip_bfloat16* WoutT  = (__hip_bfloat16*)WoutT_f;
  __hip_bfloat16* W1T    = (__hip_bfloat16*)W1T_f;
  __hip_bfloat16* W2T    = (__hip_bfloat16*)W2T_f;
  __hip_bfloat16* Pbuf   = (__hip_bfloat16*)tqkv;    // P1 / P2 overlay
  __hip_bfloat16* hid    = (__hip_bfloat16*)tqkv;    // FF hidden overlay (x path)
  __hip_bfloat16* hid_kc = (__hip_bfloat16*)kcqkv;   // FF hidden overlay (kx+cls)

  const size_t CL_OFF = (size_t)2 * Bb * MK * Dd;
  const size_t AT_OFF = CL_OFF + (size_t)Bb * Dd;

  for (int l = 0; l < 2; ++l) {
    const float* xp  = (l == 0) ? x_in  : x_s;
    const float* kxp = (l == 0) ? kx_in : kx_s;
    const float* cp  = (l == 0) ? c_in  : c_s;
    ln_kernel<<<Bb * Nn, 64, 0, stream>>>(xp,  ln1g + l * Dd, ln1b + l * Dd, xn,  xn_bf);
    ln_kernel<<<Bb * MK, 64, 0, stream>>>(kxp, ln1g + l * Dd, ln1b + l * Dd, kxn, kxn_bf);
    ln_kernel<<<Bb,      64, 0, stream>>>(cp,  ln1g + l * Dd, ln1b + l * Dd, cn,  cn_bf);

    const float* Wq = Wqkv + (size_t)l * Dd * QLD;
    const float* Wo = Woutw + (size_t)l * Dd * Dd;
    const float* bo = boutw + (size_t)l * Dd;
    const float* W1l = W1 + (size_t)l * Dd * MLPD;
    const float* b1l = b1 + (size_t)l * MLPD;
    const float* W2l = W2 + (size_t)l * MLPD * Dd;
    const float* b2l = b2 + (size_t)l * Dd;
    wtrans_kernel<<<dim3(QLD / 64, Dd / 64), 256, 0, stream>>>(Wq, WqkvT, Dd, QLD);
    wtrans_kernel<<<dim3(Dd / 64, Dd / 64), 256, 0, stream>>>(Wo, WoutT, Dd, Dd);
    wtrans_kernel<<<dim3(MLPD / 64, Dd / 64), 256, 0, stream>>>(W1l, W1T, Dd, MLPD);
    wtrans_kernel<<<dim3(Dd / 64, MLPD / 64), 256, 0, stream>>>(W2l, W2T, MLPD, Dd);

    // QKV (x rows; then kx+cls rows in one GEMM)
    {
      GArgs g = ga_base();
      g.A = (const short*)xn_bf; g.lda = Dd;
      g.Bt = (const short*)WqkvT; g.ldb = Dd;
      g.C = tqkv; g.ldc = QLD;
      g.M = Bb * Nn; g.N = QLD; g.K = Dd;
      mgemm<128, 128, 0><<<dim3(QLD / 128, Bb * Nn / 128, 1), 256, 0, stream>>>(g);
      g.A = (const short*)kcxn_bf; g.C = kcqkv; g.M = MKC;
      mgemm<128, 128, 0><<<dim3(QLD / 128, (MKC + 127) / 128, 1), 256, 0, stream>>>(g);
    }

    split_kernel<true><<<(Bb * Nn * 128) / 256, 256, 0, stream>>>(tqkv, tq_s, tk_hi, Nn);
    split_kernel<false><<<(Bb * MK * 128) / 256, 256, 0, stream>>>(kqkv, kq_hi, kk_s, MK);
    vtrans_kernel<<<dim3(32, Nn / 64), 256, 0, stream>>>(tqkv, tvT, Nn);
    vtrans_kernel<<<dim3(32, MK / 64), 256, 0, stream>>>(kqkv, kvT, MK);

    // ---- x-path attention ----
    for (int ch = 0; ch < 2; ++ch) {
      GArgs g = ga_base();
      g.A = (const short*)(tq_s + (size_t)ch * 16 * Nn * 128); g.asb = (long)Nn * 128; g.lda = 128;
      g.Bt = (const short*)(kk_s + (size_t)ch * 16 * MK * 128); g.bsb = (long)MK * 128; g.ldb = 128;
      g.C = S; g.czi = (long)Nn * MK; g.czo = 8L * Nn * MK; g.ldc = MK;
      g.rowm = mask; g.rms = Nn; g.colm = kmask; g.cms = MK;
      g.z0 = ch * 16; g.M = Nn; g.N = MK; g.K = 128;
      mgemm<128, 128, 1><<<dim3(MK / 128, Nn / 128, 16), 256, 0, stream>>>(g);
      softmax_x_kernel<<<dim3(Nn / 16, 16), 256, 0, stream>>>(
          S, rd, Pbuf, out + AT_OFF + (size_t)l * 32 * MK * Nn, ch * 16);
    }
    {
      GArgs g = ga_base();
      g.A = (const short*)Pbuf; g.asb = (long)Nn * MK; g.lda = MK;
      g.Bt = (const short*)kvT; g.bsb = (long)64 * MK; g.ldb = MK;
      g.Cb = x_pre; g.czo = (long)Nn * Dd; g.czi = 64; g.ldc = Dd;
      g.M = Nn; g.N = 64; g.K = MK;
      mgemm<128, 64, 4><<<dim3(1, Nn / 128, 32), 256, 0, stream>>>(g);
    }
    // ---- k-path attention ----
    for (int ch = 0; ch < 2; ++ch) {
      GArgs g = ga_base();
      g.A = (const short*)(kq_hi + (size_t)ch * 16 * MK * 64); g.asb = (long)MK * 64; g.lda = 64;
      g.Bt = (const short*)(tk_hi + (size_t)ch * 16 * Nn * 64); g.bsb = (long)Nn * 64; g.ldb = 64;
      g.C = S; g.czi = (long)MK * Nn; g.czo = 8L * MK * Nn; g.ldc = Nn;
      g.rowm = kmask; g.rms = MK; g.colm = mask; g.cms = Nn;
      g.z0 = ch * 16; g.M = MK; g.N = Nn; g.K = 64;
      mgemm<128, 128, 1><<<dim3(Nn / 128, MK / 128, 16), 256, 0, stream>>>(g);
      softmax_k_kernel<<<dim3(MK, 16), 256, 0, stream>>>(S, rd, Pbuf, ch * 16);
    }
    {
      GArgs g = ga_base();
      g.A = (const short*)Pbuf; g.asb = (long)MK * Nn; g.lda = Nn;
      g.Bt = (const short*)tvT; g.bsb = (long)64 * Nn; g.ldb = Nn;
      g.Cb = kx_pre; g.czo = (long)MK * Dd; g.czi = 64; g.ldc = Dd;
      g.M = MK; g.N = 64; g.K = Nn;
      mgemm<128, 64, 4><<<dim3(1, MK / 128, 32), 256, 0, stream>>>(g);
    }
    attn_c_kernel<<<Bb * Hh, 256, 0, stream>>>(cqkv, kqkv, mask, kmask, c_pre);

    // ---- Wout + residual (x rows; then kx+cls rows) ----
    {
      GArgs g = ga_base();
      g.A = (const short*)x_pre; g.lda = Dd;
      g.Bt = (const short*)WoutT; g.ldb = Dd;
      g.C = x_s; g.ldc = Dd; g.bias = bo; g.res = xn; g.ldr = Dd;
      g.M = Bb * Nn; g.N = Dd; g.K = Dd;
      mgemm<128, 128, 2><<<dim3(Dd / 128, Bb * Nn / 128, 1), 256, 0, stream>>>(g);
      g.A = (const short*)kc_pre; g.C = kc_s; g.res = kcxn; g.M = MKC;
      mgemm<128, 128, 2><<<dim3(Dd / 128, (MKC + 127) / 128, 1), 256, 0, stream>>>(g);
    }

    // ---- FF x ----
    ln_kernel<<<Bb * Nn, 64, 0, stream>>>(x_s, ln2g + l * Dd, ln2b + l * Dd, xn, xn_bf);
    {
      GArgs g = ga_base();
      g.A = (const short*)xn_bf; g.lda = Dd;
      g.Bt = (const short*)W1T; g.ldb = Dd;
      g.Cb = hid; g.ldc = MLPD; g.bias = b1l;
      g.M = Bb * Nn; g.N = MLPD; g.K = Dd;
      mgemm<128, 128, 3><<<dim3(MLPD / 128, Bb * Nn / 128, 1), 256, 0, stream>>>(g);
      GArgs h = ga_base();
      h.A = (const short*)hid; h.lda = MLPD;
      h.Bt = (const short*)W2T; h.ldb = MLPD;
      h.C = x_s; h.ldc = Dd; h.bias = b2l; h.res = x_s; h.ldr = Dd;
      h.M = Bb * Nn; h.N = Dd; h.K = MLPD;
      mgemm<128, 128, 2><<<dim3(Dd / 128, Bb * Nn / 128, 1), 256, 0, stream>>>(h);
    }
    // ---- FF kx+cls (one GEMM pair over concatenated rows) ----
    ln_kernel<<<MKC, 64, 0, stream>>>(kc_s, ln2g + l * Dd, ln2b + l * Dd, kcxn, kcxn_bf);
    {
      GArgs g = ga_base();
      g.A = (const short*)kcxn_bf; g.lda = Dd;
      g.Bt = (const short*)W1T; g.ldb = Dd;
      g.Cb = hid_kc; g.ldc = MLPD; g.bias = b1l;
      g.M = MKC; g.N = MLPD; g.K = Dd;
      mgemm<128, 128, 3><<<dim3(MLPD / 128, (MKC + 127) / 128, 1), 256, 0, stream>>>(g);
      GArgs h = ga_base();
      h.A = (const short*)hid_kc; h.lda = MLPD;
      h.Bt = (const short*)W2T; h.ldb = MLPD;
      h.C = kc_s; h.ldc = Dd; h.bias = b2l; h.res = kc_s; h.ldr = Dd;
      h.M = MKC; h.N = Dd; h.K = MLPD;
      mgemm<128, 128, 2><<<dim3(Dd / 128, (MKC + 127) / 128, 1), 256, 0, stream>>>(h);
    }

    kreps_kernel<<<(Bb * MK * Dd) / 256, 256, 0, stream>>>(kx_s, kmask,
                                                           out + (size_t)l * Bb * MK * Dd);
  }
  cout_kernel<<<(Bb * Dd) / 256, 256, 0, stream>>>(c_s, out + CL_OFF);
}

// Round 6
// 938.105 us; speedup vs baseline: 4.7833x; 1.3300x over previous
//
#include <hip/hip_runtime.h>
#include <hip/hip_bf16.h>
#include <cstddef>

#define DEV __device__ __forceinline__

constexpr int Bb  = 4;
constexpr int Nn  = 2048;
constexpr int MK  = 256;
constexpr int Dd  = 512;
constexpr int Hh  = 8;
constexpr int DH  = 64;
constexpr int QLD = 1536;   // qkv row stride (3*512)
constexpr int MLPD = 2048;
constexpr int MKC = Bb * MK + Bb;   // kx rows + cls rows, concatenated (1028)
constexpr float SCALE = 0.125f;   // 64^-0.5
constexpr float NEGV  = -1e9f;

typedef __attribute__((ext_vector_type(8))) short short8;
typedef __attribute__((ext_vector_type(4))) float f32x4;

DEV float4 ldf4(const float* p) { return *reinterpret_cast<const float4*>(p); }

// async global->LDS, 16B per lane, linear LDS dest (wave-uniform base + lane*16)
DEV void gload16(const short* g, short* l) {
  __builtin_amdgcn_global_load_lds(
      (const __attribute__((address_space(1))) void*)g,
      (__attribute__((address_space(3))) void*)l, 16, 0, 0);
}

DEV float waveMax(float v) {
#pragma unroll
  for (int o = 32; o; o >>= 1) v = fmaxf(v, __shfl_xor(v, o));
  return v;
}
DEV float waveSum(float v) {
#pragma unroll
  for (int o = 32; o; o >>= 1) v += __shfl_xor(v, o);
  return v;
}
DEV float blockMax256(float v, float* red) {
  v = waveMax(v);
  __syncthreads();
  if ((threadIdx.x & 63) == 0) red[threadIdx.x >> 6] = v;
  __syncthreads();
  return fmaxf(fmaxf(red[0], red[1]), fmaxf(red[2], red[3]));
}
DEV float blockSum256(float v, float* red) {
  v = waveSum(v);
  __syncthreads();
  if ((threadIdx.x & 63) == 0) red[threadIdx.x >> 6] = v;
  __syncthreads();
  return red[0] + red[1] + red[2] + red[3];
}
DEV float gelu_f(float x) { return 0.5f * x * (1.f + erff(x * 0.70710678118654752f)); }

// ---------------- LayerNorm: one wave per 512-float row, dual f32+bf16 out ----------------
__global__ __launch_bounds__(64)
void ln_kernel(const float* __restrict__ in, const float* __restrict__ gw,
               const float* __restrict__ bw, float* __restrict__ out,
               __hip_bfloat16* __restrict__ outb) {
  const int row = blockIdx.x;
  const int t = threadIdx.x;
  const float* p = in + (size_t)row * Dd + t * 8;
  float4 v0 = ldf4(p), v1 = ldf4(p + 4);
  float s = v0.x + v0.y + v0.z + v0.w + v1.x + v1.y + v1.z + v1.w;
  float q = v0.x*v0.x + v0.y*v0.y + v0.z*v0.z + v0.w*v0.w
          + v1.x*v1.x + v1.y*v1.y + v1.z*v1.z + v1.w*v1.w;
  s = waveSum(s); q = waveSum(q);
  const float mu = s * (1.f / Dd);
  const float rstd = rsqrtf(fmaxf(q * (1.f / Dd) - mu * mu, 0.f) + 1e-5f);
  float4 g0 = ldf4(gw + t * 8), g1 = ldf4(gw + t * 8 + 4);
  float4 b0 = ldf4(bw + t * 8), b1 = ldf4(bw + t * 8 + 4);
  float o[8];
  o[0] = (v0.x - mu) * rstd * g0.x + b0.x;
  o[1] = (v0.y - mu) * rstd * g0.y + b0.y;
  o[2] = (v0.z - mu) * rstd * g0.z + b0.z;
  o[3] = (v0.w - mu) * rstd * g0.w + b0.w;
  o[4] = (v1.x - mu) * rstd * g1.x + b1.x;
  o[5] = (v1.y - mu) * rstd * g1.y + b1.y;
  o[6] = (v1.z - mu) * rstd * g1.z + b1.z;
  o[7] = (v1.w - mu) * rstd * g1.w + b1.w;
  float* op = out + (size_t)row * Dd + t * 8;
  *reinterpret_cast<float4*>(op)     = make_float4(o[0], o[1], o[2], o[3]);
  *reinterpret_cast<float4*>(op + 4) = make_float4(o[4], o[5], o[6], o[7]);
  if (outb) {
    __hip_bfloat16* ob = outb + (size_t)row * Dd + t * 8;
#pragma unroll
    for (int e = 0; e < 8; ++e) ob[e] = __float2bfloat16(o[e]);
  }
}

// ---------------- bf16 MFMA GEMM (global_load_lds staging, linear LDS) ----------------
// C[M,N] = A[M,K] @ Bt[N,K]^T, batched over blockIdx.z. 256 threads.
// EPI: 0 = f32 write; 1 = mask+scale f32 (scores); 2 = +bias +res f32;
//      3 = +bias, gelu, bf16 write; 4 = bf16 write.
struct GArgs {
  const short* A;  long asb; int lda;
  const short* Bt; long bsb; int ldb;
  float* C; __hip_bfloat16* Cb;
  long czo, czi; int ldc;
  const float* bias;
  const float* res; int ldr;
  const float* rowm; int rms;
  const float* colm; int cms;
  int z0, M, N, K;
};

template<int BM, int BN, int EPI>
__global__ __launch_bounds__(256)
void mgemm(GArgs g) {
  constexpr int WMW = (BN >= 128) ? 2 : 4;
  constexpr int WNW = 4 / WMW;
  constexpr int WM = BM / WMW, WN = BN / WNW;
  constexpr int FM = WM / 16, FN = WN / 16;
  __shared__ __align__(16) short As[BM * 64];
  __shared__ __align__(16) short Bs[BN * 64];
  const int tid = threadIdx.x, l = tid & 63, w = tid >> 6;
  const int wm = (WNW == 2) ? (w >> 1) : w;
  const int wn = (WNW == 2) ? (w & 1) : 0;
  const int bx = blockIdx.x, by = blockIdx.y, z = blockIdx.z;
  const short* Ab = g.A + (size_t)z * g.asb;
  const short* Bb_ = g.Bt + (size_t)z * g.bsb;
  f32x4 acc[FM][FN] = {};
  const int lr = l & 15, lg = l >> 4;

  for (int k0 = 0; k0 < g.K; k0 += 64) {
    __syncthreads();
#pragma unroll
    for (int it = 0; it < BM / 32; ++it) {
      int idx = tid + it * 256, r = idx >> 3, c8 = (idx & 7) * 8;
      int gm = by * BM + r;
      if (gm >= g.M) gm = g.M - 1;           // clamp: rows independent in MFMA, masked at write
      gload16(Ab + (size_t)gm * g.lda + k0 + c8, As + idx * 8);
    }
#pragma unroll
    for (int it = 0; it < BN / 32; ++it) {
      int idx = tid + it * 256, r = idx >> 3, c8 = (idx & 7) * 8;
      int gn = bx * BN + r;
      gload16(Bb_ + (size_t)gn * g.ldb + k0 + c8, Bs + idx * 8);
    }
    __syncthreads();                         // compiler inserts vmcnt(0) drain here
#pragma unroll
    for (int ks = 0; ks < 2; ++ks) {
      const int kb = ks * 32 + lg * 8;       // shorts
      short8 a[FM], b[FN];
#pragma unroll
      for (int fm = 0; fm < FM; ++fm) {
        int r = wm * WM + fm * 16 + lr;
        a[fm] = *reinterpret_cast<const short8*>(As + r * 64 + kb);
      }
#pragma unroll
      for (int fn = 0; fn < FN; ++fn) {
        int r = wn * WN + fn * 16 + lr;
        b[fn] = *reinterpret_cast<const short8*>(Bs + r * 64 + kb);
      }
#pragma unroll
      for (int fm = 0; fm < FM; ++fm)
#pragma unroll
        for (int fn = 0; fn < FN; ++fn)
          acc[fm][fn] = __builtin_amdgcn_mfma_f32_16x16x32_bf16(a[fm], b[fn], acc[fm][fn], 0, 0, 0);
    }
  }

  const int bg = (g.z0 + z) >> 3;
  const size_t zoff = (size_t)(z >> 3) * g.czo + (size_t)(z & 7) * g.czi;
#pragma unroll
  for (int fm = 0; fm < FM; ++fm) {
#pragma unroll
    for (int fn = 0; fn < FN; ++fn) {
#pragma unroll
      for (int r = 0; r < 4; ++r) {
        int m = by * BM + wm * WM + fm * 16 + lg * 4 + r;
        int n = bx * BN + wn * WN + fn * 16 + lr;
        if (m >= g.M) continue;
        float v = acc[fm][fn][r];
        size_t coff = zoff + (size_t)m * g.ldc + n;
        if (EPI == 0) {
          g.C[coff] = v;
        } else if (EPI == 1) {
          float rm = g.rowm[(size_t)bg * g.rms + m];
          float cm = g.colm[(size_t)bg * g.cms + n];
          g.C[coff] = (rm * cm < 0.5f) ? NEGV : v * SCALE;
        } else if (EPI == 2) {
          v += g.bias[n] + g.res[(size_t)m * g.ldr + n];
          g.C[coff] = v;
        } else if (EPI == 3) {
          v = gelu_f(v + g.bias[n]);
          g.Cb[coff] = __float2bfloat16(v);
        } else {
          g.Cb[coff] = __float2bfloat16(v);
        }
      }
    }
  }
}

template<int BM, int BN, int EPI>
static void launch_mgemm(const GArgs& g, int zdim, hipStream_t s) {
  dim3 grid((g.N + BN - 1) / BN, (g.M + BM - 1) / BM, zdim);
  mgemm<BM, BN, EPI><<<grid, 256, 0, s>>>(g);
}

// ---------------- weight transpose: f32 [K][N] -> bf16 [N][K] ----------------
__global__ __launch_bounds__(256)
void wtrans_kernel(const float* __restrict__ W, __hip_bfloat16* __restrict__ WT,
                   int K, int N) {
  __shared__ float t[64][65];
  const int n0 = blockIdx.x * 64, k0 = blockIdx.y * 64;
  const int tid = threadIdx.x;
#pragma unroll
  for (int it = 0; it < 4; ++it) {
    int idx = tid + it * 256, r = idx >> 4, f = idx & 15;
    float4 v = ldf4(W + (size_t)(k0 + r) * N + n0 + f * 4);
    t[r][f * 4 + 0] = v.x; t[r][f * 4 + 1] = v.y;
    t[r][f * 4 + 2] = v.z; t[r][f * 4 + 3] = v.w;
  }
  __syncthreads();
#pragma unroll
  for (int it = 0; it < 4; ++it) {
    int idx = tid + it * 256, r = idx >> 4, c4 = (idx & 15) * 4;
    __hip_bfloat16* op = WT + (size_t)(n0 + r) * K + k0 + c4;
#pragma unroll
    for (int e = 0; e < 4; ++e) op[e] = __float2bfloat16(t[c4 + e][r]);
  }
}

// ---------------- qkv split: hi/lo bf16 operand prep ----------------
template<bool Q_SPLIT>
__global__ __launch_bounds__(256)
void split_kernel(const float* __restrict__ qkv, __hip_bfloat16* __restrict__ qout,
                  __hip_bfloat16* __restrict__ kout, int T) {
  const int idx = blockIdx.x * 256 + threadIdx.x;     // B*T*128 items
  const int token = idx >> 7, c8 = (idx & 127) * 8;
  const int b = token / T, i = token - b * T;
  const float* p = qkv + (size_t)token * QLD + c8;
  float v[8];
  float4 a = ldf4(p), c = ldf4(p + 4);
  v[0]=a.x; v[1]=a.y; v[2]=a.z; v[3]=a.w; v[4]=c.x; v[5]=c.y; v[6]=c.z; v[7]=c.w;
  if (c8 < 512) {
    int h = c8 >> 6, d = c8 & 63;
    if (Q_SPLIT) {
      __hip_bfloat16* q = qout + ((size_t)((b * 8 + h) * T + i)) * 128 + d;
#pragma unroll
      for (int e = 0; e < 8; ++e) {
        __hip_bfloat16 hi = __float2bfloat16(v[e]);
        q[e] = hi;
        q[64 + e] = __float2bfloat16(v[e] - __bfloat162float(hi));
      }
    } else {
      __hip_bfloat16* q = qout + ((size_t)((b * 8 + h) * T + i)) * 64 + d;
#pragma unroll
      for (int e = 0; e < 8; ++e) q[e] = __float2bfloat16(v[e]);
    }
  } else {
    int cc = c8 - 512, h = cc >> 6, d = cc & 63;
    if (Q_SPLIT) {
      __hip_bfloat16* k = kout + ((size_t)((b * 8 + h) * T + i)) * 64 + d;
#pragma unroll
      for (int e = 0; e < 8; ++e) k[e] = __float2bfloat16(v[e]);
    } else {
      __hip_bfloat16* k = kout + ((size_t)((b * 8 + h) * T + i)) * 128 + d;
#pragma unroll
      for (int e = 0; e < 8; ++e) {
        __hip_bfloat16 hi = __float2bfloat16(v[e]);
        k[e] = hi;
        k[64 + e] = __float2bfloat16(v[e] - __bfloat162float(hi));
      }
    }
  }
}

// ---------------- v transpose: qkv v-part -> bf16 [bh][d][token] ----------------
__global__ __launch_bounds__(256)
void vtrans_kernel(const float* __restrict__ qkv, __hip_bfloat16* __restrict__ vT, int T) {
  __shared__ float t[64][65];
  const int bh = blockIdx.x, b = bh >> 3, h = bh & 7;
  const int i0 = blockIdx.y * 64;
  const int tid = threadIdx.x;
#pragma unroll
  for (int it = 0; it < 4; ++it) {
    int idx = tid + it * 256, r = idx >> 4, f = idx & 15;
    float4 v = ldf4(qkv + (size_t)(b * T + i0 + r) * QLD + 2 * Dd + h * 64 + f * 4);
    t[r][f * 4 + 0] = v.x; t[r][f * 4 + 1] = v.y;
    t[r][f * 4 + 2] = v.z; t[r][f * 4 + 3] = v.w;
  }
  __syncthreads();
#pragma unroll
  for (int it = 0; it < 4; ++it) {
    int idx = tid + it * 256, d = idx >> 4, c4 = (idx & 15) * 4;
    __hip_bfloat16* op = vT + (size_t)(bh * 64 + d) * T + i0 + c4;
#pragma unroll
    for (int e = 0; e < 4; ++e) op[e] = __float2bfloat16(t[c4 + e][d]);
  }
}

// ---------------- x-path softmax (dual e1/e24) + rd + atten write ----------------
__global__ __launch_bounds__(256)
void softmax_x_kernel(const float* __restrict__ S, const float* __restrict__ rd,
                      __hip_bfloat16* __restrict__ P1, float* __restrict__ atten, int z0) {
  __shared__ float rd_s[MK][17];
  __shared__ float e24_s[16][261];
  const int tid = threadIdx.x, l = tid & 63, w = tid >> 6;
  const int zloc = blockIdx.y, bh = z0 + zloc, b = bh >> 3;
  const int i0 = blockIdx.x * 16;
#pragma unroll
  for (int it = 0; it < 4; ++it) {
    int idx = tid + it * 256, j = idx >> 2, f = idx & 3;
    float4 v = ldf4(rd + (size_t)(b * MK + j) * Nn + i0 + f * 4);
    rd_s[j][f * 4 + 0] = v.x; rd_s[j][f * 4 + 1] = v.y;
    rd_s[j][f * 4 + 2] = v.z; rd_s[j][f * 4 + 3] = v.w;
  }
  __syncthreads();
#pragma unroll
  for (int rr = 0; rr < 4; ++rr) {
    const int r = w * 4 + rr;
    const int i = i0 + r;
    const float* sp = S + ((size_t)zloc * Nn + i) * MK;
    float d0 = sp[l], d1 = sp[l + 64], d2 = sp[l + 128], d3 = sp[l + 192];
    float mx = fmaxf(fmaxf(d0, d1), fmaxf(d2, d3));
    mx = waveMax(mx);
    float e10 = __expf(d0 - mx), e11 = __expf(d1 - mx), e12 = __expf(d2 - mx), e13 = __expf(d3 - mx);
    float f0 = __expf(24.f * (d0 - mx)), f1 = __expf(24.f * (d1 - mx));
    float f2 = __expf(24.f * (d2 - mx)), f3 = __expf(24.f * (d3 - mx));
    float s1 = waveSum(e10 + e11 + e12 + e13);
    float s24 = waveSum(f0 + f1 + f2 + f3);
    const float i1 = 1.f / s1, i24 = 1.f / s24;
    __hip_bfloat16* pp = P1 + ((size_t)bh * Nn + i) * MK;
    float r0 = rd_s[l][r], r1 = rd_s[l + 64][r], r2 = rd_s[l + 128][r], r3 = rd_s[l + 192][r];
    pp[l]       = __float2bfloat16(e10 * i1 * r0);
    pp[l + 64]  = __float2bfloat16(e11 * i1 * r1);
    pp[l + 128] = __float2bfloat16(e12 * i1 * r2);
    pp[l + 192] = __float2bfloat16(e13 * i1 * r3);
    e24_s[r][l]       = f0 * i24 * r0;
    e24_s[r][l + 64]  = f1 * i24 * r1;
    e24_s[r][l + 128] = f2 * i24 * r2;
    e24_s[r][l + 192] = f3 * i24 * r3;
  }
  __syncthreads();
  const int iL = l & 15, jg = l >> 4;
#pragma unroll
  for (int jj = 0; jj < 16; ++jj) {
    int j = w * 64 + jj * 4 + jg;
    atten[((size_t)bh * MK + j) * Nn + i0 + iL] = e24_s[iL][j];
  }
}

// ---------------- k-path softmax + rd ----------------
__global__ __launch_bounds__(256)
void softmax_k_kernel(const float* __restrict__ S, const float* __restrict__ rd,
                      __hip_bfloat16* __restrict__ P2, int z0) {
  __shared__ float red8[8];
  const int tid = threadIdx.x;
  const int j = blockIdx.x, zloc = blockIdx.y, bh = z0 + zloc, b = bh >> 3;
  const float* row = S + ((size_t)zloc * MK + j) * Nn;
  float d[8];
  float lm = -3.4e38f;
#pragma unroll
  for (int c = 0; c < 8; ++c) { d[c] = row[c * 256 + tid]; lm = fmaxf(lm, d[c]); }
  const float mx = blockMax256(lm, red8);
  float ls = 0.f;
#pragma unroll
  for (int c = 0; c < 8; ++c) { d[c] = __expf(d[c] - mx); ls += d[c]; }
  const float s = blockSum256(ls, red8);
  const float inv = 1.f / s;
  const float* rp = rd + (size_t)(b * MK + j) * Nn;
  __hip_bfloat16* pp = P2 + ((size_t)bh * MK + j) * Nn;
#pragma unroll
  for (int c = 0; c < 8; ++c)
    pp[c * 256 + tid] = __float2bfloat16(d[c] * inv * rp[c * 256 + tid]);
}

// ------------- cls-token attention: grid B*H, block 256, bf16 out -------------
__global__ __launch_bounds__(256)
void attn_c_kernel(const float* __restrict__ cqkv, const float* __restrict__ kqkv,
                   const float* __restrict__ mask, const float* __restrict__ kmask,
                   __hip_bfloat16* __restrict__ c_pre) {
  __shared__ __align__(16) float kv_s[MK][DH];
  __shared__ __align__(16) float q_s[DH];
  __shared__ float pbuf[MK];
  __shared__ float red8[8];
  __shared__ float redpv[4][DH];
  const int tid = threadIdx.x;
  const int bh = blockIdx.x, b = bh >> 3, h = bh & 7;
  const float* vp = kqkv + ((size_t)(b * MK + tid)) * QLD + 2 * Dd + h * DH;
#pragma unroll
  for (int q4 = 0; q4 < 16; ++q4)
    *reinterpret_cast<float4*>(&kv_s[tid][q4 * 4]) = ldf4(vp + q4 * 4);
  if (tid < DH) q_s[tid] = cqkv[(size_t)b * QLD + h * DH + tid];
  __syncthreads();
  const float* kp = kqkv + ((size_t)(b * MK + tid)) * QLD + Dd + h * DH;
  float dot = 0.f;
#pragma unroll
  for (int q4 = 0; q4 < 16; ++q4) {
    float4 kv4 = ldf4(kp + q4 * 4);
    float4 qv = ldf4(&q_s[q4 * 4]);
    dot = fmaf(qv.x, kv4.x, dot);
    dot = fmaf(qv.y, kv4.y, dot);
    dot = fmaf(qv.z, kv4.z, dot);
    dot = fmaf(qv.w, kv4.w, dot);
  }
  const float dm = (mask[(size_t)b * Nn] * kmask[b * MK + tid] < 0.5f) ? NEGV : dot * SCALE;
  const float mx = blockMax256(dm, red8);
  const float e = __expf(dm - mx);
  const float s = blockSum256(e, red8);
  pbuf[tid] = e / s;
  __syncthreads();
  const int d = tid & 63, g = tid >> 6;
  float acc = 0.f;
#pragma unroll 8
  for (int jj = 0; jj < 64; ++jj)
    acc = fmaf(pbuf[g * 64 + jj], kv_s[g * 64 + jj][d], acc);
  redpv[g][d] = acc;
  __syncthreads();
  if (tid < DH)
    c_pre[(size_t)b * Dd + h * DH + tid] = __float2bfloat16(
        redpv[0][tid] + redpv[1][tid] + redpv[2][tid] + redpv[3][tid]);
}

// ------------- output writers (float32 outputs) -------------
__global__ void kreps_kernel(const float* __restrict__ kx, const float* __restrict__ kmask,
                             float* __restrict__ o) {
  const int idx = blockIdx.x * 256 + threadIdx.x;
  const int bj = idx >> 9;
  const float keep = (kmask[bj] >= 0.5f) ? 1.f : 0.f;
  o[idx] = kx[idx] * keep;
}
__global__ void cout_kernel(const float* __restrict__ c_s, float* __restrict__ o) {
  const int idx = blockIdx.x * 256 + threadIdx.x;
  o[idx] = c_s[idx];
}

static GArgs ga_base() { GArgs g = {}; return g; }

extern "C" void kernel_launch(void* const* d_in, const int* in_sizes, int n_in,
                              void* d_out, int out_size, void* d_ws, size_t ws_size,
                              hipStream_t stream) {
  (void)in_sizes; (void)n_in; (void)out_size; (void)ws_size;
  const float* x_in  = (const float*)d_in[0];
  const float* kx_in = (const float*)d_in[1];
  const float* rd    = (const float*)d_in[2];
  const float* c_in  = (const float*)d_in[3];
  const float* mask  = (const float*)d_in[4];
  const float* kmask = (const float*)d_in[5];
  const float* ln1g  = (const float*)d_in[6];
  const float* ln1b  = (const float*)d_in[7];
  const float* Wqkv  = (const float*)d_in[8];
  const float* Woutw = (const float*)d_in[9];
  const float* boutw = (const float*)d_in[10];
  const float* ln2g  = (const float*)d_in[11];
  const float* ln2b  = (const float*)d_in[12];
  const float* W1    = (const float*)d_in[13];
  const float* b1    = (const float*)d_in[14];
  const float* W2    = (const float*)d_in[15];
  const float* b2    = (const float*)d_in[16];
  float* out = (float*)d_out;

  float* ws = (float*)d_ws;
  size_t off = 0;
  auto alloc = [&](size_t n) { float* p = ws + off; off += (n + 15) & ~(size_t)15; return p; };
  float* x_s    = alloc((size_t)Bb * Nn * Dd);
  float* xn     = alloc((size_t)Bb * Nn * Dd);
  float* xn_bf_f = alloc((size_t)Bb * Nn * Dd / 2);
  // kx/cls concatenated buffers: cls rows appended after Bb*MK rows
  float* kc_s   = alloc((size_t)MKC * Dd);
  float* kcxn   = alloc((size_t)MKC * Dd);
  float* kcxn_bf_f = alloc((size_t)MKC * Dd / 2);
  float* kcqkv  = alloc((size_t)MKC * QLD);          // hosts hid_kc later
  float* kcpre_f = alloc((size_t)MKC * Dd / 2);
  float* tqkv   = alloc((size_t)Bb * Nn * QLD);      // hosts P / hid-x later
  float* S      = alloc((size_t)16 * Nn * MK);       // score scratch, 16 bh per chunk
  float* tq_s_f  = alloc((size_t)32 * Nn * 128 / 2);
  float* kk_s_f  = alloc((size_t)32 * MK * 128 / 2);
  float* tk_hi_f = alloc((size_t)32 * Nn * 64 / 2);
  float* kq_hi_f = alloc((size_t)32 * MK * 64 / 2);
  float* tvT_f   = alloc((size_t)32 * 64 * Nn / 2);
  float* kvT_f   = alloc((size_t)32 * 64 * MK / 2);
  float* xpre_f  = alloc((size_t)Bb * Nn * Dd / 2);
  float* WqkvT_f = alloc((size_t)QLD * Dd / 2);
  float* WoutT_f = alloc((size_t)Dd * Dd / 2);
  float* W1T_f   = alloc((size_t)MLPD * Dd / 2);
  float* W2T_f   = alloc((size_t)Dd * MLPD / 2);

  float* kx_s = kc_s;                    // rows [0, Bb*MK)
  float* c_s  = kc_s + (size_t)Bb * MK * Dd;
  float* kxn  = kcxn;
  float* cn   = kcxn + (size_t)Bb * MK * Dd;
  float* kqkv = kcqkv;
  float* cqkv = kcqkv + (size_t)Bb * MK * QLD;

  __hip_bfloat16* xn_bf  = (__hip_bfloat16*)xn_bf_f;
  __hip_bfloat16* kcxn_bf = (__hip_bfloat16*)kcxn_bf_f;
  __hip_bfloat16* kxn_bf = kcxn_bf;
  __hip_bfloat16* cn_bf  = kcxn_bf + (size_t)Bb * MK * Dd;
  __hip_bfloat16* kc_pre = (__hip_bfloat16*)kcpre_f;
  __hip_bfloat16* kx_pre = kc_pre;
  __hip_bfloat16* c_pre  = kc_pre + (size_t)Bb * MK * Dd;
  __hip_bfloat16* tq_s   = (__hip_bfloat16*)tq_s_f;
  __hip_bfloat16* kk_s   = (__hip_bfloat16*)kk_s_f;
  __hip_bfloat16* tk_hi  = (__hip_bfloat16*)tk_hi_f;
  __hip_bfloat16* kq_hi  = (__hip_bfloat16*)kq_hi_f;
  __hip_bfloat16* tvT    = (__hip_bfloat16*)tvT_f;
  __hip_bfloat16* kvT    = (__hip_bfloat16*)kvT_f;
  __hip_bfloat16* x_pre  = (__hip_bfloat16*)xpre_f;
  __hip_bfloat16* WqkvT  = (__hip_bfloat16*)WqkvT_f;
  __hip_bfloat16* WoutT  = (__hip_bfloat16*)WoutT_f;
  __hip_bfloat16* W1T    = (__hip_bfloat16*)W1T_f;
  __hip_bfloat16* W2T    = (__hip_bfloat16*)W2T_f;
  __hip_bfloat16* Pbuf   = (__hip_bfloat16*)tqkv;    // P1 / P2 overlay
  __hip_bfloat16* hid    = (__hip_bfloat16*)tqkv;    // FF hidden overlay (x path)
  __hip_bfloat16* hid_kc = (__hip_bfloat16*)kcqkv;   // FF hidden overlay (kx+cls)

  const size_t CL_OFF = (size_t)2 * Bb * MK * Dd;
  const size_t AT_OFF = CL_OFF + (size_t)Bb * Dd;

  for (int l = 0; l < 2; ++l) {
    const float* xp  = (l == 0) ? x_in  : x_s;
    const float* kxp = (l == 0) ? kx_in : kx_s;
    const float* cp  = (l == 0) ? c_in  : c_s;
    ln_kernel<<<Bb * Nn, 64, 0, stream>>>(xp,  ln1g + l * Dd, ln1b + l * Dd, xn,  xn_bf);
    ln_kernel<<<Bb * MK, 64, 0, stream>>>(kxp, ln1g + l * Dd, ln1b + l * Dd, kxn, kxn_bf);
    ln_kernel<<<Bb,      64, 0, stream>>>(cp,  ln1g + l * Dd, ln1b + l * Dd, cn,  cn_bf);

    const float* Wq = Wqkv + (size_t)l * Dd * QLD;
    const float* Wo = Woutw + (size_t)l * Dd * Dd;
    const float* bo = boutw + (size_t)l * Dd;
    const float* W1l = W1 + (size_t)l * Dd * MLPD;
    const float* b1l = b1 + (size_t)l * MLPD;
    const float* W2l = W2 + (size_t)l * MLPD * Dd;
    const float* b2l = b2 + (size_t)l * Dd;
    wtrans_kernel<<<dim3(QLD / 64, Dd / 64), 256, 0, stream>>>(Wq, WqkvT, Dd, QLD);
    wtrans_kernel<<<dim3(Dd / 64, Dd / 64), 256, 0, stream>>>(Wo, WoutT, Dd, Dd);
    wtrans_kernel<<<dim3(MLPD / 64, Dd / 64), 256, 0, stream>>>(W1l, W1T, Dd, MLPD);
    wtrans_kernel<<<dim3(Dd / 64, MLPD / 64), 256, 0, stream>>>(W2l, W2T, MLPD, Dd);

    // QKV (x rows; then kx+cls rows)
    {
      GArgs g = ga_base();
      g.A = (const short*)xn_bf; g.lda = Dd;
      g.Bt = (const short*)WqkvT; g.ldb = Dd;
      g.C = tqkv; g.ldc = QLD;
      g.M = Bb * Nn; g.N = QLD; g.K = Dd;
      launch_mgemm<128, 128, 0>(g, 1, stream);
      g.A = (const short*)kcxn_bf; g.C = kcqkv; g.M = MKC;
      launch_mgemm<64, 128, 0>(g, 1, stream);
    }

    split_kernel<true><<<(Bb * Nn * 128) / 256, 256, 0, stream>>>(tqkv, tq_s, tk_hi, Nn);
    split_kernel<false><<<(Bb * MK * 128) / 256, 256, 0, stream>>>(kqkv, kq_hi, kk_s, MK);
    vtrans_kernel<<<dim3(32, Nn / 64), 256, 0, stream>>>(tqkv, tvT, Nn);
    vtrans_kernel<<<dim3(32, MK / 64), 256, 0, stream>>>(kqkv, kvT, MK);

    // ---- x-path attention ----
    for (int ch = 0; ch < 2; ++ch) {
      GArgs g = ga_base();
      g.A = (const short*)(tq_s + (size_t)ch * 16 * Nn * 128); g.asb = (long)Nn * 128; g.lda = 128;
      g.Bt = (const short*)(kk_s + (size_t)ch * 16 * MK * 128); g.bsb = (long)MK * 128; g.ldb = 128;
      g.C = S; g.czi = (long)Nn * MK; g.czo = 8L * Nn * MK; g.ldc = MK;
      g.rowm = mask; g.rms = Nn; g.colm = kmask; g.cms = MK;
      g.z0 = ch * 16; g.M = Nn; g.N = MK; g.K = 128;
      launch_mgemm<128, 128, 1>(g, 16, stream);
      softmax_x_kernel<<<dim3(Nn / 16, 16), 256, 0, stream>>>(
          S, rd, Pbuf, out + AT_OFF + (size_t)l * 32 * MK * Nn, ch * 16);
    }
    {
      GArgs g = ga_base();
      g.A = (const short*)Pbuf; g.asb = (long)Nn * MK; g.lda = MK;
      g.Bt = (const short*)kvT; g.bsb = (long)64 * MK; g.ldb = MK;
      g.Cb = x_pre; g.czo = (long)Nn * Dd; g.czi = 64; g.ldc = Dd;
      g.M = Nn; g.N = 64; g.K = MK;
      launch_mgemm<128, 64, 4>(g, 32, stream);
    }
    // ---- k-path attention ----
    for (int ch = 0; ch < 2; ++ch) {
      GArgs g = ga_base();
      g.A = (const short*)(kq_hi + (size_t)ch * 16 * MK * 64); g.asb = (long)MK * 64; g.lda = 64;
      g.Bt = (const short*)(tk_hi + (size_t)ch * 16 * Nn * 64); g.bsb = (long)Nn * 64; g.ldb = 64;
      g.C = S; g.czi = (long)MK * Nn; g.czo = 8L * MK * Nn; g.ldc = Nn;
      g.rowm = kmask; g.rms = MK; g.colm = mask; g.cms = Nn;
      g.z0 = ch * 16; g.M = MK; g.N = Nn; g.K = 64;
      launch_mgemm<128, 128, 1>(g, 16, stream);
      softmax_k_kernel<<<dim3(MK, 16), 256, 0, stream>>>(S, rd, Pbuf, ch * 16);
    }
    {
      GArgs g = ga_base();
      g.A = (const short*)Pbuf; g.asb = (long)MK * Nn; g.lda = Nn;
      g.Bt = (const short*)tvT; g.bsb = (long)64 * Nn; g.ldb = Nn;
      g.Cb = kx_pre; g.czo = (long)MK * Dd; g.czi = 64; g.ldc = Dd;
      g.M = MK; g.N = 64; g.K = Nn;
      launch_mgemm<64, 64, 4>(g, 32, stream);
    }
    attn_c_kernel<<<Bb * Hh, 256, 0, stream>>>(cqkv, kqkv, mask, kmask, c_pre);

    // ---- Wout + residual (x rows; then kx+cls rows) ----
    {
      GArgs g = ga_base();
      g.A = (const short*)x_pre; g.lda = Dd;
      g.Bt = (const short*)WoutT; g.ldb = Dd;
      g.C = x_s; g.ldc = Dd; g.bias = bo; g.res = xn; g.ldr = Dd;
      g.M = Bb * Nn; g.N = Dd; g.K = Dd;
      launch_mgemm<128, 64, 2>(g, 1, stream);
      g.A = (const short*)kc_pre; g.C = kc_s; g.res = kcxn; g.M = MKC;
      launch_mgemm<64, 64, 2>(g, 1, stream);
    }

    // ---- FF x ----
    ln_kernel<<<Bb * Nn, 64, 0, stream>>>(x_s, ln2g + l * Dd, ln2b + l * Dd, xn, xn_bf);
    {
      GArgs g = ga_base();
      g.A = (const short*)xn_bf; g.lda = Dd;
      g.Bt = (const short*)W1T; g.ldb = Dd;
      g.Cb = hid; g.ldc = MLPD; g.bias = b1l;
      g.M = Bb * Nn; g.N = MLPD; g.K = Dd;
      launch_mgemm<128, 128, 3>(g, 1, stream);
      GArgs h = ga_base();
      h.A = (const short*)hid; h.lda = MLPD;
      h.Bt = (const short*)W2T; h.ldb = MLPD;
      h.C = x_s; h.ldc = Dd; h.bias = b2l; h.res = x_s; h.ldr = Dd;
      h.M = Bb * Nn; h.N = Dd; h.K = MLPD;
      launch_mgemm<128, 64, 2>(h, 1, stream);
    }
    // ---- FF kx+cls ----
    ln_kernel<<<MKC, 64, 0, stream>>>(kc_s, ln2g + l * Dd, ln2b + l * Dd, kcxn, kcxn_bf);
    {
      GArgs g = ga_base();
      g.A = (const short*)kcxn_bf; g.lda = Dd;
      g.Bt = (const short*)W1T; g.ldb = Dd;
      g.Cb = hid_kc; g.ldc = MLPD; g.bias = b1l;
      g.M = MKC; g.N = MLPD; g.K = Dd;
      launch_mgemm<64, 128, 3>(g, 1, stream);
      GArgs h = ga_base();
      h.A = (const short*)hid_kc; h.lda = MLPD;
      h.Bt = (const short*)W2T; h.ldb = MLPD;
      h.C = kc_s; h.ldc = Dd; h.bias = b2l; h.res = kc_s; h.ldr = Dd;
      h.M = MKC; h.N = Dd; h.K = MLPD;
      launch_mgemm<64, 64, 2>(h, 1, stream);
    }

    kreps_kernel<<<(Bb * MK * Dd) / 256, 256, 0, stream>>>(kx_s, kmask,
                                                           out + (size_t)l * Bb * MK * Dd);
  }
  cout_kernel<<<(Bb * Dd) / 256, 256, 0, stream>>>(c_s, out + CL_OFF);
}